// Round 1
// baseline (1458.700 us; speedup 1.0000x reference)
//
#include <hip/hip_runtime.h>
#include <math.h>

#define N_NODES 50000
#define N_EDGES 400000
#define DIM 16
#define BOND 4

// ---------------------------------------------------------------------------
// K0: tiny precompute: M_B = U_B@V_B [16x16], M_A = U_A@V_A [4x4]
// (low-rank collapse: (X@U)@V == X@(U@V); msg_C / w_node / W_lin are dead code
//  since only out_edges reaches the returned log_softmax)
// ---------------------------------------------------------------------------
__global__ __launch_bounds__(256) void precompute_kernel(
    const float* __restrict__ U_B, const float* __restrict__ V_B,
    const float* __restrict__ U_A, const float* __restrict__ V_A,
    float* __restrict__ M_B, float* __restrict__ M_A) {
  int t = threadIdx.x;
  int i = t >> 4, j = t & 15;
  float acc = 0.f;
  for (int r = 0; r < 512; ++r) acc += U_B[i * 512 + r] * V_B[r * 16 + j];
  M_B[i * 16 + j] = acc;
  if (t < 16) {
    int a = t >> 2, b = t & 3;
    float s = 0.f;
    for (int r = 0; r < 512; ++r) s += U_A[a * 512 + r] * V_A[r * 4 + b];
    M_A[a * 4 + b] = s;
  }
}

// ---------------------------------------------------------------------------
// K1: out = relu(x @ W_lin0 + b_lin0)   [N,16]
// ---------------------------------------------------------------------------
__global__ __launch_bounds__(256) void lin0_kernel(
    const float* __restrict__ x, const float* __restrict__ W,
    const float* __restrict__ b, float* __restrict__ out) {
  __shared__ float sW[256];
  __shared__ float sb[16];
  int t = threadIdx.x;
  sW[t] = W[t];
  if (t < 16) sb[t] = b[t];
  __syncthreads();
  int n = blockIdx.x * blockDim.x + t;
  if (n >= N_NODES) return;
  float xr[16];
#pragma unroll
  for (int d = 0; d < 16; ++d) xr[d] = x[n * 16 + d];
#pragma unroll
  for (int k = 0; k < 16; ++k) {
    float acc = sb[k];
#pragma unroll
    for (int d = 0; d < 16; ++d) acc += xr[d] * sW[d * 16 + k];
    out[n * 16 + k] = fmaxf(acc, 0.f);
  }
}

// ---------------------------------------------------------------------------
// K2: deg[dst] += 1 per edge (edge_index fixed -> once per launch)
// ---------------------------------------------------------------------------
__global__ __launch_bounds__(256) void deg_kernel(const int* __restrict__ ei,
                                                  float* __restrict__ deg) {
  int e = blockIdx.x * blockDim.x + threadIdx.x;
  if (e >= N_EDGES) return;
  atomicAdd(&deg[ei[N_EDGES + e]], 1.0f);
}

// ---------------------------------------------------------------------------
// K3: per-edge NNConv message + scatter-add into agg.
// m[e,k] = sum_d out[src,d] * ( b_e2[d*16+k] + sum_h he[e,h]*W_e2[h,256][d*16+k] )
// he recomputed from edge_attr (cheap: 4x32). W_e2/b_e2 accesses are
// wave-uniform -> scalar-load path expected.
// ---------------------------------------------------------------------------
__global__ __launch_bounds__(256) void edge_msg_kernel(
    const int* __restrict__ ei, const float* __restrict__ ea,
    const float* __restrict__ We1, const float* __restrict__ be1,
    const float* __restrict__ We2, const float* __restrict__ be2,
    const float* __restrict__ out, float* __restrict__ agg) {
  int e = blockIdx.x * blockDim.x + threadIdx.x;
  if (e >= N_EDGES) return;
  int src = ei[e];
  int dst = ei[N_EDGES + e];

  float eav[4];
#pragma unroll
  for (int bb = 0; bb < 4; ++bb) eav[bb] = ea[e * 4 + bb];

  float he[32];
#pragma unroll
  for (int h = 0; h < 32; ++h) {
    float a = be1[h];
#pragma unroll
    for (int bb = 0; bb < 4; ++bb) a += eav[bb] * We1[bb * 32 + h];
    he[h] = fmaxf(a, 0.f);
  }

  float o[16];
#pragma unroll
  for (int d = 0; d < 16; ++d) o[d] = out[src * 16 + d];

  float acc[16];
#pragma unroll
  for (int k = 0; k < 16; ++k) acc[k] = 0.f;

  // bias part of We
#pragma unroll
  for (int d = 0; d < 16; ++d) {
    float od = o[d];
#pragma unroll
    for (int k = 0; k < 16; ++k) acc[k] += od * be2[d * 16 + k];
  }

  // main contraction: 32 x 16 x 16 FMAs
#pragma unroll 2
  for (int h = 0; h < 32; ++h) {
    float hh = he[h];
    const float* __restrict__ w = &We2[h * 256];
#pragma unroll
    for (int d = 0; d < 16; ++d) {
      float od = o[d] * hh;
#pragma unroll
      for (int k = 0; k < 16; ++k) acc[k] += od * w[d * 16 + k];
    }
  }

#pragma unroll
  for (int k = 0; k < 16; ++k) atomicAdd(&agg[dst * 16 + k], acc[k]);
}

// ---------------------------------------------------------------------------
// K4: node update: m = relu(out@W_root + b_conv + agg/max(deg,1));
//     out = GRU(m, out)   (h and out are the same buffer in the reference)
// ---------------------------------------------------------------------------
__global__ __launch_bounds__(256) void gru_kernel(
    const float* __restrict__ Wroot, const float* __restrict__ bconv,
    const float* __restrict__ Wih, const float* __restrict__ bih,
    const float* __restrict__ Whh, const float* __restrict__ bhh,
    const float* __restrict__ agg, const float* __restrict__ deg,
    float* __restrict__ out) {
  int n = blockIdx.x * blockDim.x + threadIdx.x;
  if (n >= N_NODES) return;

  float hprev[16];
#pragma unroll
  for (int d = 0; d < 16; ++d) hprev[d] = out[n * 16 + d];
  float s = 1.0f / fmaxf(deg[n], 1.0f);

  float m[16];
#pragma unroll
  for (int k = 0; k < 16; ++k) {
    float a = bconv[k] + agg[n * 16 + k] * s;
#pragma unroll
    for (int d = 0; d < 16; ++d) a += hprev[d] * Wroot[d * 16 + k];
    m[k] = fmaxf(a, 0.f);
  }

  float hnew[16];
#pragma unroll
  for (int k = 0; k < 16; ++k) {
    float gir = bih[k], giz = bih[16 + k], gin = bih[32 + k];
    float ghr = bhh[k], ghz = bhh[16 + k], ghn = bhh[32 + k];
#pragma unroll
    for (int d = 0; d < 16; ++d) {
      gir += m[d] * Wih[k * 16 + d];
      giz += m[d] * Wih[(16 + k) * 16 + d];
      gin += m[d] * Wih[(32 + k) * 16 + d];
      ghr += hprev[d] * Whh[k * 16 + d];
      ghz += hprev[d] * Whh[(16 + k) * 16 + d];
      ghn += hprev[d] * Whh[(32 + k) * 16 + d];
    }
    float r = 1.f / (1.f + expf(-(gir + ghr)));
    float z = 1.f / (1.f + expf(-(giz + ghz)));
    float ng = tanhf(gin + r * ghn);
    hnew[k] = (1.f - z) * ng + z * hprev[k];
  }
#pragma unroll
  for (int k = 0; k < 16; ++k) out[n * 16 + k] = hnew[k];
}

// ---------------------------------------------------------------------------
// K5: everything after the GRU loop, fused per node. Only the out_edges
// branch matters (returned value); node-branch update of `out` is dead code.
// ---------------------------------------------------------------------------
__global__ __launch_bounds__(256) void final_kernel(
    const float* __restrict__ out, const int* __restrict__ node_type,
    const float* __restrict__ Wlin1, const float* __restrict__ blin1,
    const float* __restrict__ Wup, const float* __restrict__ bup,
    const float* __restrict__ Wdown, const float* __restrict__ bdown,
    const float* __restrict__ M_B, const float* __restrict__ M_A,
    const float* __restrict__ wedge, const float* __restrict__ Wline,
    const float* __restrict__ bline, float* __restrict__ res) {
  int n = blockIdx.x * blockDim.x + threadIdx.x;
  if (n >= N_NODES) return;

  float o[16];
#pragma unroll
  for (int d = 0; d < 16; ++d) o[d] = out[n * 16 + d];

  // out_edges = relu(out @ W_lin1 + b_lin1)
  float oe[4];
#pragma unroll
  for (int b = 0; b < 4; ++b) {
    float a = blin1[b];
#pragma unroll
    for (int d = 0; d < 16; ++d) a += o[d] * Wlin1[d * 4 + b];
    oe[b] = fmaxf(a, 0.f);
  }

  // out_combine = ev ? oe @ W_up + b_up : out
  bool ev = (node_type[n] == 2);
  float oc[16];
#pragma unroll
  for (int d = 0; d < 16; ++d) {
    float up = bup[d];
#pragma unroll
    for (int b = 0; b < 4; ++b) up += oe[b] * Wup[b * 16 + d];
    oc[d] = ev ? up : o[d];
  }

  // msg_B = relu(oc @ M_B)
  float msgB[16];
#pragma unroll
  for (int k = 0; k < 16; ++k) {
    float a = 0.f;
#pragma unroll
    for (int d = 0; d < 16; ++d) a += oc[d] * M_B[d * 16 + k];
    msgB[k] = fmaxf(a, 0.f);
  }

  // msg_to_edge_B = msg_B @ W_down + b_down ; msg_to_edge_A = relu(oe @ M_A)
  float oef[4];
#pragma unroll
  for (int b = 0; b < 4; ++b) {
    float mb = bdown[b];
#pragma unroll
    for (int k = 0; k < 16; ++k) mb += msgB[k] * Wdown[k * 4 + b];
    float ma = 0.f;
#pragma unroll
    for (int a = 0; a < 4; ++a) ma += oe[a] * M_A[a * 4 + b];
    ma = fmaxf(ma, 0.f);
    oef[b] = wedge[b] * (ma * mb);  // w_edge * combine_edge_msg
  }

  // oe_final = oe + relu(cem @ W_line + b_line)
  float fin[4];
#pragma unroll
  for (int b = 0; b < 4; ++b) {
    float a = bline[b];
#pragma unroll
    for (int c = 0; c < 4; ++c) a += oef[c] * Wline[c * 4 + b];
    fin[b] = oe[b] + fmaxf(a, 0.f);
  }

  // log_softmax over 4
  float mx = fmaxf(fmaxf(fin[0], fin[1]), fmaxf(fin[2], fin[3]));
  float se = expf(fin[0] - mx) + expf(fin[1] - mx) + expf(fin[2] - mx) +
             expf(fin[3] - mx);
  float lse = mx + logf(se);
#pragma unroll
  for (int b = 0; b < 4; ++b) res[n * 4 + b] = fin[b] - lse;
}

// ---------------------------------------------------------------------------
extern "C" void kernel_launch(void* const* d_in, const int* in_sizes, int n_in,
                              void* d_out, int out_size, void* d_ws,
                              size_t ws_size, hipStream_t stream) {
  const float* x      = (const float*)d_in[0];
  const int* node_type = (const int*)d_in[1];
  const int* ei       = (const int*)d_in[2];
  const float* ea     = (const float*)d_in[3];
  const float* W_lin0 = (const float*)d_in[4];
  const float* b_lin0 = (const float*)d_in[5];
  const float* W_root = (const float*)d_in[6];
  const float* b_conv = (const float*)d_in[7];
  const float* W_e1   = (const float*)d_in[8];
  const float* b_e1   = (const float*)d_in[9];
  const float* W_e2   = (const float*)d_in[10];
  const float* b_e2   = (const float*)d_in[11];
  const float* W_ih   = (const float*)d_in[12];
  const float* b_ih   = (const float*)d_in[13];
  const float* W_hh   = (const float*)d_in[14];
  const float* b_hh   = (const float*)d_in[15];
  const float* W_lin1 = (const float*)d_in[16];
  const float* b_lin1 = (const float*)d_in[17];
  const float* W_up   = (const float*)d_in[18];
  const float* b_up   = (const float*)d_in[19];
  const float* W_down = (const float*)d_in[20];
  const float* b_down = (const float*)d_in[21];
  const float* U_B    = (const float*)d_in[22];
  const float* V_B    = (const float*)d_in[23];
  // d_in[24], d_in[25] = U_C, V_C : dead code (msg_C only feeds dead node out)
  const float* U_A    = (const float*)d_in[26];
  const float* V_A    = (const float*)d_in[27];
  // d_in[28..30] = w_node, W_lin, b_lin : dead code
  const float* w_edge = (const float*)d_in[31];
  const float* W_line = (const float*)d_in[32];
  const float* b_line = (const float*)d_in[33];

  float* ws  = (float*)d_ws;
  float* out = ws;                     // N*16
  float* agg = out + N_NODES * 16;     // N*16
  float* deg = agg + N_NODES * 16;     // N
  float* M_B = deg + N_NODES;          // 256
  float* M_A = M_B + 256;              // 16

  hipMemsetAsync(deg, 0, N_NODES * sizeof(float), stream);
  precompute_kernel<<<1, 256, 0, stream>>>(U_B, V_B, U_A, V_A, M_B, M_A);
  lin0_kernel<<<(N_NODES + 255) / 256, 256, 0, stream>>>(x, W_lin0, b_lin0, out);
  deg_kernel<<<(N_EDGES + 255) / 256, 256, 0, stream>>>(ei, deg);

  for (int it = 0; it < 3; ++it) {
    hipMemsetAsync(agg, 0, N_NODES * 16 * sizeof(float), stream);
    edge_msg_kernel<<<(N_EDGES + 255) / 256, 256, 0, stream>>>(
        ei, ea, W_e1, b_e1, W_e2, b_e2, out, agg);
    gru_kernel<<<(N_NODES + 255) / 256, 256, 0, stream>>>(
        W_root, b_conv, W_ih, b_ih, W_hh, b_hh, agg, deg, out);
  }

  final_kernel<<<(N_NODES + 255) / 256, 256, 0, stream>>>(
      out, node_type, W_lin1, b_lin1, W_up, b_up, W_down, b_down, M_B, M_A,
      w_edge, W_line, b_line, (float*)d_out);
}

// Round 2
// 1075.492 us; speedup vs baseline: 1.3563x; 1.3563x over previous
//
#include <hip/hip_runtime.h>
#include <math.h>

#define N_NODES 50000
#define N_EDGES 400000
#define DIM 16
#define BOND 4
#define NBLK 196  // ceil(N_NODES/256)

// ---------------------------------------------------------------------------
// K0: tiny precompute: M_B = U_B@V_B [16x16], M_A = U_A@V_A [4x4]
// (low-rank collapse; msg_C / w_node / W_lin are dead code since only
//  out_edges reaches the returned log_softmax)
// ---------------------------------------------------------------------------
__global__ __launch_bounds__(256) void precompute_kernel(
    const float* __restrict__ U_B, const float* __restrict__ V_B,
    const float* __restrict__ U_A, const float* __restrict__ V_A,
    float* __restrict__ M_B, float* __restrict__ M_A) {
  int t = threadIdx.x;
  int i = t >> 4, j = t & 15;
  float acc = 0.f;
  for (int r = 0; r < 512; ++r) acc += U_B[i * 512 + r] * V_B[r * 16 + j];
  M_B[i * 16 + j] = acc;
  if (t < 16) {
    int a = t >> 2, b = t & 3;
    float s = 0.f;
    for (int r = 0; r < 512; ++r) s += U_A[a * 512 + r] * V_A[r * 4 + b];
    M_A[a * 4 + b] = s;
  }
}

// ---------------------------------------------------------------------------
// K1: out = relu(x @ W_lin0 + b_lin0)   [N,16]
// ---------------------------------------------------------------------------
__global__ __launch_bounds__(256) void lin0_kernel(
    const float* __restrict__ x, const float* __restrict__ W,
    const float* __restrict__ b, float* __restrict__ out) {
  __shared__ float sW[256];
  __shared__ float sb[16];
  int t = threadIdx.x;
  sW[t] = W[t];
  if (t < 16) sb[t] = b[t];
  __syncthreads();
  int n = blockIdx.x * blockDim.x + t;
  if (n >= N_NODES) return;
  float xr[16];
#pragma unroll
  for (int d = 0; d < 16; ++d) xr[d] = x[n * 16 + d];
#pragma unroll
  for (int k = 0; k < 16; ++k) {
    float acc = sb[k];
#pragma unroll
    for (int d = 0; d < 16; ++d) acc += xr[d] * sW[d * 16 + k];
    out[n * 16 + k] = fmaxf(acc, 0.f);
  }
}

// ---------------------------------------------------------------------------
// CSR build (counting sort by dst). Int atomics only, once per launch.
// ---------------------------------------------------------------------------
__global__ __launch_bounds__(256) void deg_count_kernel(
    const int* __restrict__ ei, int* __restrict__ degI) {
  int e = blockIdx.x * 256 + threadIdx.x;
  if (e < N_EDGES) atomicAdd(&degI[ei[N_EDGES + e]], 1);
}

__global__ __launch_bounds__(256) void block_sum_kernel(
    const int* __restrict__ degI, int* __restrict__ blk) {
  __shared__ int s[256];
  int t = threadIdx.x;
  int n = blockIdx.x * 256 + t;
  s[t] = (n < N_NODES) ? degI[n] : 0;
  __syncthreads();
  for (int off = 128; off > 0; off >>= 1) {
    if (t < off) s[t] += s[t + off];
    __syncthreads();
  }
  if (t == 0) blk[blockIdx.x] = s[0];
}

__global__ __launch_bounds__(256) void block_scan_kernel(
    const int* __restrict__ blk, int* __restrict__ blk_off,
    int* __restrict__ row_off) {
  __shared__ int s[256];
  int t = threadIdx.x;
  int v = (t < NBLK) ? blk[t] : 0;
  s[t] = v;
  __syncthreads();
  for (int off = 1; off < 256; off <<= 1) {
    int x = (t >= off) ? s[t - off] : 0;
    __syncthreads();
    s[t] += x;
    __syncthreads();
  }
  if (t < NBLK) blk_off[t] = s[t] - v;  // exclusive
  if (t == 0) row_off[N_NODES] = N_EDGES;
}

__global__ __launch_bounds__(256) void node_scan_kernel(
    const int* __restrict__ degI, const int* __restrict__ blk_off,
    int* __restrict__ row_off) {
  __shared__ int s[256];
  int t = threadIdx.x;
  int n = blockIdx.x * 256 + t;
  int d = (n < N_NODES) ? degI[n] : 0;
  s[t] = d;
  __syncthreads();
  for (int off = 1; off < 256; off <<= 1) {
    int x = (t >= off) ? s[t - off] : 0;
    __syncthreads();
    s[t] += x;
    __syncthreads();
  }
  if (n < N_NODES) row_off[n] = blk_off[blockIdx.x] + s[t] - d;
}

__global__ __launch_bounds__(256) void slot_kernel(const int* __restrict__ ei,
                                                   int* __restrict__ cur,
                                                   int* __restrict__ slot) {
  int e = blockIdx.x * 256 + threadIdx.x;
  if (e < N_EDGES) slot[e] = atomicAdd(&cur[ei[N_EDGES + e]], 1);
}

// ---------------------------------------------------------------------------
// K3: per-edge NNConv message, written dst-sorted (slot[e]) — NO atomics.
// m[e,k] = sum_d out[src,d] * ( b_e2[d*16+k] + sum_h he[e,h]*W_e2[h][d*16+k] )
// ---------------------------------------------------------------------------
__global__ __launch_bounds__(256) void edge_msg_kernel(
    const int* __restrict__ ei, const float* __restrict__ ea,
    const float* __restrict__ We1, const float* __restrict__ be1,
    const float* __restrict__ We2, const float* __restrict__ be2,
    const float* __restrict__ out, const int* __restrict__ slot,
    float* __restrict__ m_buf) {
  int e = blockIdx.x * blockDim.x + threadIdx.x;
  if (e >= N_EDGES) return;
  int src = ei[e];
  int sl = slot[e];

  float4 eav = ((const float4*)ea)[e];

  float he[32];
#pragma unroll
  for (int h = 0; h < 32; ++h) {
    float a = be1[h] + eav.x * We1[h] + eav.y * We1[32 + h] +
              eav.z * We1[64 + h] + eav.w * We1[96 + h];
    he[h] = fmaxf(a, 0.f);
  }

  float o[16];
  {
    const float4* op = (const float4*)(out + src * 16);
#pragma unroll
    for (int q = 0; q < 4; ++q) {
      float4 v = op[q];
      o[q * 4 + 0] = v.x; o[q * 4 + 1] = v.y;
      o[q * 4 + 2] = v.z; o[q * 4 + 3] = v.w;
    }
  }

  float acc[16];
#pragma unroll
  for (int k = 0; k < 16; ++k) acc[k] = 0.f;

  // bias part of We
#pragma unroll
  for (int d = 0; d < 16; ++d) {
    float od = o[d];
#pragma unroll
    for (int k = 0; k < 16; ++k) acc[k] += od * be2[d * 16 + k];
  }

  // main contraction: 32 x 16 x 16 FMAs (We2 reads are wave-uniform -> s_load)
#pragma unroll 2
  for (int h = 0; h < 32; ++h) {
    float hh = he[h];
    const float* __restrict__ w = &We2[h * 256];
#pragma unroll
    for (int d = 0; d < 16; ++d) {
      float od = o[d] * hh;
#pragma unroll
      for (int k = 0; k < 16; ++k) acc[k] += od * w[d * 16 + k];
    }
  }

  float4* mb = (float4*)(m_buf + (size_t)sl * 16);
#pragma unroll
  for (int q = 0; q < 4; ++q) {
    float4 v;
    v.x = acc[q * 4 + 0]; v.y = acc[q * 4 + 1];
    v.z = acc[q * 4 + 2]; v.w = acc[q * 4 + 3];
    mb[q] = v;
  }
}

// ---------------------------------------------------------------------------
// K3b: gather: agg[n,:] = sum over dst-sorted message range. 16 lanes/node.
// ---------------------------------------------------------------------------
__global__ __launch_bounds__(256) void gather_kernel(
    const int* __restrict__ row_off, const float* __restrict__ m_buf,
    float* __restrict__ agg) {
  int n = blockIdx.x * 16 + (threadIdx.x >> 4);
  int lane = threadIdx.x & 15;
  if (n >= N_NODES) return;
  int s = row_off[n], eend = row_off[n + 1];
  float sum = 0.f;
  for (int j = s; j < eend; ++j) sum += m_buf[(size_t)j * 16 + lane];
  agg[n * 16 + lane] = sum;
}

// ---------------------------------------------------------------------------
// K4: node update: m = relu(out@W_root + b_conv + agg/max(deg,1));
//     out = GRU(m, out)
// ---------------------------------------------------------------------------
__global__ __launch_bounds__(256) void gru_kernel(
    const float* __restrict__ Wroot, const float* __restrict__ bconv,
    const float* __restrict__ Wih, const float* __restrict__ bih,
    const float* __restrict__ Whh, const float* __restrict__ bhh,
    const float* __restrict__ agg, const int* __restrict__ degI,
    float* __restrict__ out) {
  int n = blockIdx.x * blockDim.x + threadIdx.x;
  if (n >= N_NODES) return;

  float hprev[16];
#pragma unroll
  for (int d = 0; d < 16; ++d) hprev[d] = out[n * 16 + d];
  float s = 1.0f / fmaxf((float)degI[n], 1.0f);

  float m[16];
#pragma unroll
  for (int k = 0; k < 16; ++k) {
    float a = bconv[k] + agg[n * 16 + k] * s;
#pragma unroll
    for (int d = 0; d < 16; ++d) a += hprev[d] * Wroot[d * 16 + k];
    m[k] = fmaxf(a, 0.f);
  }

  float hnew[16];
#pragma unroll
  for (int k = 0; k < 16; ++k) {
    float gir = bih[k], giz = bih[16 + k], gin = bih[32 + k];
    float ghr = bhh[k], ghz = bhh[16 + k], ghn = bhh[32 + k];
#pragma unroll
    for (int d = 0; d < 16; ++d) {
      gir += m[d] * Wih[k * 16 + d];
      giz += m[d] * Wih[(16 + k) * 16 + d];
      gin += m[d] * Wih[(32 + k) * 16 + d];
      ghr += hprev[d] * Whh[k * 16 + d];
      ghz += hprev[d] * Whh[(16 + k) * 16 + d];
      ghn += hprev[d] * Whh[(32 + k) * 16 + d];
    }
    float r = 1.f / (1.f + expf(-(gir + ghr)));
    float z = 1.f / (1.f + expf(-(giz + ghz)));
    float ng = tanhf(gin + r * ghn);
    hnew[k] = (1.f - z) * ng + z * hprev[k];
  }
#pragma unroll
  for (int k = 0; k < 16; ++k) out[n * 16 + k] = hnew[k];
}

// ---------------------------------------------------------------------------
// K5: post-GRU tail fused per node (only the out_edges branch is live).
// ---------------------------------------------------------------------------
__global__ __launch_bounds__(256) void final_kernel(
    const float* __restrict__ out, const int* __restrict__ node_type,
    const float* __restrict__ Wlin1, const float* __restrict__ blin1,
    const float* __restrict__ Wup, const float* __restrict__ bup,
    const float* __restrict__ Wdown, const float* __restrict__ bdown,
    const float* __restrict__ M_B, const float* __restrict__ M_A,
    const float* __restrict__ wedge, const float* __restrict__ Wline,
    const float* __restrict__ bline, float* __restrict__ res) {
  int n = blockIdx.x * blockDim.x + threadIdx.x;
  if (n >= N_NODES) return;

  float o[16];
#pragma unroll
  for (int d = 0; d < 16; ++d) o[d] = out[n * 16 + d];

  float oe[4];
#pragma unroll
  for (int b = 0; b < 4; ++b) {
    float a = blin1[b];
#pragma unroll
    for (int d = 0; d < 16; ++d) a += o[d] * Wlin1[d * 4 + b];
    oe[b] = fmaxf(a, 0.f);
  }

  bool ev = (node_type[n] == 2);
  float oc[16];
#pragma unroll
  for (int d = 0; d < 16; ++d) {
    float up = bup[d];
#pragma unroll
    for (int b = 0; b < 4; ++b) up += oe[b] * Wup[b * 16 + d];
    oc[d] = ev ? up : o[d];
  }

  float msgB[16];
#pragma unroll
  for (int k = 0; k < 16; ++k) {
    float a = 0.f;
#pragma unroll
    for (int d = 0; d < 16; ++d) a += oc[d] * M_B[d * 16 + k];
    msgB[k] = fmaxf(a, 0.f);
  }

  float oef[4];
#pragma unroll
  for (int b = 0; b < 4; ++b) {
    float mb = bdown[b];
#pragma unroll
    for (int k = 0; k < 16; ++k) mb += msgB[k] * Wdown[k * 4 + b];
    float ma = 0.f;
#pragma unroll
    for (int a = 0; a < 4; ++a) ma += oe[a] * M_A[a * 4 + b];
    ma = fmaxf(ma, 0.f);
    oef[b] = wedge[b] * (ma * mb);
  }

  float fin[4];
#pragma unroll
  for (int b = 0; b < 4; ++b) {
    float a = bline[b];
#pragma unroll
    for (int c = 0; c < 4; ++c) a += oef[c] * Wline[c * 4 + b];
    fin[b] = oe[b] + fmaxf(a, 0.f);
  }

  float mx = fmaxf(fmaxf(fin[0], fin[1]), fmaxf(fin[2], fin[3]));
  float se = expf(fin[0] - mx) + expf(fin[1] - mx) + expf(fin[2] - mx) +
             expf(fin[3] - mx);
  float lse = mx + logf(se);
#pragma unroll
  for (int b = 0; b < 4; ++b) res[n * 4 + b] = fin[b] - lse;
}

// ---------------------------------------------------------------------------
extern "C" void kernel_launch(void* const* d_in, const int* in_sizes, int n_in,
                              void* d_out, int out_size, void* d_ws,
                              size_t ws_size, hipStream_t stream) {
  const float* x       = (const float*)d_in[0];
  const int* node_type = (const int*)d_in[1];
  const int* ei        = (const int*)d_in[2];
  const float* ea      = (const float*)d_in[3];
  const float* W_lin0  = (const float*)d_in[4];
  const float* b_lin0  = (const float*)d_in[5];
  const float* W_root  = (const float*)d_in[6];
  const float* b_conv  = (const float*)d_in[7];
  const float* W_e1    = (const float*)d_in[8];
  const float* b_e1    = (const float*)d_in[9];
  const float* W_e2    = (const float*)d_in[10];
  const float* b_e2    = (const float*)d_in[11];
  const float* W_ih    = (const float*)d_in[12];
  const float* b_ih    = (const float*)d_in[13];
  const float* W_hh    = (const float*)d_in[14];
  const float* b_hh    = (const float*)d_in[15];
  const float* W_lin1  = (const float*)d_in[16];
  const float* b_lin1  = (const float*)d_in[17];
  const float* W_up    = (const float*)d_in[18];
  const float* b_up    = (const float*)d_in[19];
  const float* W_down  = (const float*)d_in[20];
  const float* b_down  = (const float*)d_in[21];
  const float* U_B     = (const float*)d_in[22];
  const float* V_B     = (const float*)d_in[23];
  // d_in[24..25] U_C,V_C and d_in[28..30] w_node,W_lin,b_lin : dead code
  const float* U_A     = (const float*)d_in[26];
  const float* V_A     = (const float*)d_in[27];
  const float* w_edge  = (const float*)d_in[31];
  const float* W_line  = (const float*)d_in[32];
  const float* b_line  = (const float*)d_in[33];

  float* ws    = (float*)d_ws;
  float* out   = ws;                        // N*16
  float* agg   = out + N_NODES * 16;        // N*16
  float* m_buf = agg + N_NODES * 16;        // E*16  (64B-aligned)
  float* M_B   = m_buf + (size_t)N_EDGES * 16;  // 256
  float* M_A   = M_B + 256;                 // 16
  int* degI    = (int*)(M_A + 16);          // N
  int* row_off = degI + N_NODES;            // N+1
  int* blk_sum = row_off + N_NODES + 1;     // 256
  int* blk_off = blk_sum + 256;             // 256
  int* cur     = blk_off + 256;             // N
  int* slot    = cur + N_NODES;             // E

  hipMemsetAsync(degI, 0, N_NODES * sizeof(int), stream);
  precompute_kernel<<<1, 256, 0, stream>>>(U_B, V_B, U_A, V_A, M_B, M_A);
  lin0_kernel<<<(N_NODES + 255) / 256, 256, 0, stream>>>(x, W_lin0, b_lin0, out);

  // CSR build (once per launch; edge_index constant within a call)
  deg_count_kernel<<<(N_EDGES + 255) / 256, 256, 0, stream>>>(ei, degI);
  block_sum_kernel<<<NBLK, 256, 0, stream>>>(degI, blk_sum);
  block_scan_kernel<<<1, 256, 0, stream>>>(blk_sum, blk_off, row_off);
  node_scan_kernel<<<NBLK, 256, 0, stream>>>(degI, blk_off, row_off);
  hipMemcpyAsync(cur, row_off, N_NODES * sizeof(int),
                 hipMemcpyDeviceToDevice, stream);
  slot_kernel<<<(N_EDGES + 255) / 256, 256, 0, stream>>>(ei, cur, slot);

  for (int it = 0; it < 3; ++it) {
    edge_msg_kernel<<<(N_EDGES + 255) / 256, 256, 0, stream>>>(
        ei, ea, W_e1, b_e1, W_e2, b_e2, out, slot, m_buf);
    gather_kernel<<<(N_NODES + 15) / 16, 256, 0, stream>>>(row_off, m_buf, agg);
    gru_kernel<<<(N_NODES + 255) / 256, 256, 0, stream>>>(
        W_root, b_conv, W_ih, b_ih, W_hh, b_hh, agg, degI, out);
  }

  final_kernel<<<(N_NODES + 255) / 256, 256, 0, stream>>>(
      out, node_type, W_lin1, b_lin1, W_up, b_up, W_down, b_down, M_B, M_A,
      w_edge, W_line, b_line, (float*)d_out);
}

// Round 3
// 496.283 us; speedup vs baseline: 2.9393x; 2.1671x over previous
//
#include <hip/hip_runtime.h>
#include <hip/hip_bf16.h>
#include <math.h>

#define N_NODES 50000
#define N_EDGES 400000
#define DIM 16
#define BOND 4
#define NBLK 196    // ceil(N_NODES/256)
#define NCHUNK 25000  // N_EDGES / 16
#define EDGE_GRID 784

typedef __attribute__((ext_vector_type(8))) short short8;
typedef __attribute__((ext_vector_type(4))) float f32x4;

// ---------------------------------------------------------------------------
// K0: tiny precompute: M_B = U_B@V_B [16x16], M_A = U_A@V_A [4x4]
// (low-rank collapse; msg_C / w_node / W_lin are dead code since only
//  out_edges reaches the returned log_softmax)
// ---------------------------------------------------------------------------
__global__ __launch_bounds__(256) void precompute_kernel(
    const float* __restrict__ U_B, const float* __restrict__ V_B,
    const float* __restrict__ U_A, const float* __restrict__ V_A,
    float* __restrict__ M_B, float* __restrict__ M_A) {
  int t = threadIdx.x;
  int i = t >> 4, j = t & 15;
  float acc = 0.f;
  for (int r = 0; r < 512; ++r) acc += U_B[i * 512 + r] * V_B[r * 16 + j];
  M_B[i * 16 + j] = acc;
  if (t < 16) {
    int a = t >> 2, b = t & 3;
    float s = 0.f;
    for (int r = 0; r < 512; ++r) s += U_A[a * 512 + r] * V_A[r * 4 + b];
    M_A[a * 4 + b] = s;
  }
}

// ---------------------------------------------------------------------------
// K1: out = relu(x @ W_lin0 + b_lin0)   [N,16]
// ---------------------------------------------------------------------------
__global__ __launch_bounds__(256) void lin0_kernel(
    const float* __restrict__ x, const float* __restrict__ W,
    const float* __restrict__ b, float* __restrict__ out) {
  __shared__ float sW[256];
  __shared__ float sb[16];
  int t = threadIdx.x;
  sW[t] = W[t];
  if (t < 16) sb[t] = b[t];
  __syncthreads();
  int n = blockIdx.x * blockDim.x + t;
  if (n >= N_NODES) return;
  float xr[16];
#pragma unroll
  for (int d = 0; d < 16; ++d) xr[d] = x[n * 16 + d];
#pragma unroll
  for (int k = 0; k < 16; ++k) {
    float acc = sb[k];
#pragma unroll
    for (int d = 0; d < 16; ++d) acc += xr[d] * sW[d * 16 + k];
    out[n * 16 + k] = fmaxf(acc, 0.f);
  }
}

// ---------------------------------------------------------------------------
// CSR build (counting sort by dst). Int atomics only, once per launch.
// ---------------------------------------------------------------------------
__global__ __launch_bounds__(256) void deg_count_kernel(
    const int* __restrict__ ei, int* __restrict__ degI) {
  int e = blockIdx.x * 256 + threadIdx.x;
  if (e < N_EDGES) atomicAdd(&degI[ei[N_EDGES + e]], 1);
}

__global__ __launch_bounds__(256) void block_sum_kernel(
    const int* __restrict__ degI, int* __restrict__ blk) {
  __shared__ int s[256];
  int t = threadIdx.x;
  int n = blockIdx.x * 256 + t;
  s[t] = (n < N_NODES) ? degI[n] : 0;
  __syncthreads();
  for (int off = 128; off > 0; off >>= 1) {
    if (t < off) s[t] += s[t + off];
    __syncthreads();
  }
  if (t == 0) blk[blockIdx.x] = s[0];
}

__global__ __launch_bounds__(256) void block_scan_kernel(
    const int* __restrict__ blk, int* __restrict__ blk_off,
    int* __restrict__ row_off) {
  __shared__ int s[256];
  int t = threadIdx.x;
  int v = (t < NBLK) ? blk[t] : 0;
  s[t] = v;
  __syncthreads();
  for (int off = 1; off < 256; off <<= 1) {
    int x = (t >= off) ? s[t - off] : 0;
    __syncthreads();
    s[t] += x;
    __syncthreads();
  }
  if (t < NBLK) blk_off[t] = s[t] - v;  // exclusive
  if (t == 0) row_off[N_NODES] = N_EDGES;
}

__global__ __launch_bounds__(256) void node_scan_kernel(
    const int* __restrict__ degI, const int* __restrict__ blk_off,
    int* __restrict__ row_off) {
  __shared__ int s[256];
  int t = threadIdx.x;
  int n = blockIdx.x * 256 + t;
  int d = (n < N_NODES) ? degI[n] : 0;
  s[t] = d;
  __syncthreads();
  for (int off = 1; off < 256; off <<= 1) {
    int x = (t >= off) ? s[t - off] : 0;
    __syncthreads();
    s[t] += x;
    __syncthreads();
  }
  if (n < N_NODES) row_off[n] = blk_off[blockIdx.x] + s[t] - d;
}

__global__ __launch_bounds__(256) void slot_kernel(const int* __restrict__ ei,
                                                   int* __restrict__ cur,
                                                   int* __restrict__ slot) {
  int e = blockIdx.x * 256 + threadIdx.x;
  if (e < N_EDGES) slot[e] = atomicAdd(&cur[ei[N_EDGES + e]], 1);
}

// ---------------------------------------------------------------------------
// he precompute (iteration-invariant): he[e,h]=relu(b_e1[h]+ea[e,:]@W_e1[:,h])
// stored bf16, lane-fragment layout: he_buf[e*16 + p*8 + t] (uint32) packs
// (h = 4t+p) in low half, (h = 4t+2+p) in high half, p = parity in {0,1}.
// So uint32 index s>>1 within a lane's 8 holds step s: low = s even.
// ---------------------------------------------------------------------------
__global__ __launch_bounds__(256) void he_pre_kernel(
    const float* __restrict__ ea, const float* __restrict__ We1,
    const float* __restrict__ be1, unsigned int* __restrict__ he_buf) {
  __shared__ float sW[128];
  __shared__ float sb[32];
  int t = threadIdx.x;
  if (t < 128) sW[t] = We1[t];
  if (t < 32) sb[t] = be1[t];
  __syncthreads();
  int e = blockIdx.x * 256 + t;
  if (e >= N_EDGES) return;
  float4 v = ((const float4*)ea)[e];
  float h[32];
#pragma unroll
  for (int k = 0; k < 32; ++k) {
    float a = sb[k] + v.x * sW[k] + v.y * sW[32 + k] + v.z * sW[64 + k] +
              v.w * sW[96 + k];
    h[k] = fmaxf(a, 0.f);
  }
  unsigned int u[16];
#pragma unroll
  for (int p = 0; p < 2; ++p)
#pragma unroll
    for (int tt = 0; tt < 8; ++tt) {
      float2 pr;
      pr.x = h[4 * tt + p];      // step s = 2*tt   -> h = 2s+p = 4tt+p
      pr.y = h[4 * tt + 2 + p];  // step s = 2*tt+1 -> h = 4tt+2+p
      __hip_bfloat162 b = __float22bfloat162_rn(pr);
      u[p * 8 + tt] = *(unsigned int*)&b;
    }
  uint4* dst = (uint4*)(he_buf + (size_t)e * 16);
#pragma unroll
  for (int qq = 0; qq < 4; ++qq)
    dst[qq] = make_uint4(u[4 * qq], u[4 * qq + 1], u[4 * qq + 2], u[4 * qq + 3]);
}

// ---------------------------------------------------------------------------
// K3 (MFMA): m[E,16] = Z[E,512] @ W2'[512,16],  Z[e, h*16+d] = he[e,h]*o[src,d]
// W2'[h*16+d, k] = W_e2[h, d*16+k].  16x16x32 bf16 MFMA, fp32 accumulate.
// Per wave: 16-edge chunks, grid-strided; B-fragments (all of We2 + b_e2,
// bf16) preloaded into 68 VGPRs once per wave.
// A-layout: A[m=lane&15][k=(lane>>4)*8+j]; B[k=(lane>>4)*8+j][n=lane&15];
// D: row = (lane>>4)*4+reg, col = lane&15  (verified layouts, m89/m120).
// k_global = s*32 + (lane>>4)*8 + j -> h = 2s+p, d = (q&1)*8+j.
// Extra step s=16: A = o (k<16, else 0), B = b_e2 rows (bias term).
// ---------------------------------------------------------------------------
__global__ __launch_bounds__(256) void edge_msg_mfma_kernel(
    const int* __restrict__ ei, const unsigned int* __restrict__ he_buf,
    const float* __restrict__ We2, const float* __restrict__ be2,
    const float* __restrict__ out, const int* __restrict__ slot,
    float* __restrict__ m_buf) {
  const int lane = threadIdx.x & 63;
  const int q = lane >> 4, n = lane & 15;
  const int p = q >> 1, dbase = (q & 1) * 8;

  short8 bfrag[17];
#pragma unroll
  for (int s = 0; s < 16; ++s) {
    int h = 2 * s + p;
    union { short8 v; __hip_bfloat162 b2[4]; } bf;
#pragma unroll
    for (int jj = 0; jj < 4; ++jj) {
      float2 w;
      w.x = We2[h * 256 + (dbase + 2 * jj) * 16 + n];
      w.y = We2[h * 256 + (dbase + 2 * jj + 1) * 16 + n];
      bf.b2[jj] = __float22bfloat162_rn(w);
    }
    bfrag[s] = bf.v;
  }
  {
    union { short8 v; __hip_bfloat162 b2[4]; } bf;
#pragma unroll
    for (int jj = 0; jj < 4; ++jj) {
      float2 w;
      if (q < 2) {
        w.x = be2[(dbase + 2 * jj) * 16 + n];
        w.y = be2[(dbase + 2 * jj + 1) * 16 + n];
      } else {
        w.x = 0.f; w.y = 0.f;
      }
      bf.b2[jj] = __float22bfloat162_rn(w);
    }
    bfrag[16] = bf.v;
  }

  int wave = blockIdx.x * 4 + (threadIdx.x >> 6);
  const int nw = EDGE_GRID * 4;
  for (int c = wave; c < NCHUNK; c += nw) {
    int e = c * 16 + n;  // this lane's A-row edge
    int src = ei[e];
    const uint4* hp = (const uint4*)(he_buf + (size_t)e * 16 + p * 8);
    uint4 h0 = hp[0], h1 = hp[1];
    unsigned int heu[8] = {h0.x, h0.y, h0.z, h0.w, h1.x, h1.y, h1.z, h1.w};
    const float4* op = (const float4*)(out + src * 16 + dbase);
    float4 o0 = op[0], o1 = op[1];
    float o[8] = {o0.x, o0.y, o0.z, o0.w, o1.x, o1.y, o1.z, o1.w};

    f32x4 acc = {0.f, 0.f, 0.f, 0.f};
#pragma unroll
    for (int s = 0; s < 16; ++s) {
      unsigned int hw = heu[s >> 1];
      float he_s = __uint_as_float((s & 1) ? (hw & 0xffff0000u) : (hw << 16));
      union { short8 v; __hip_bfloat162 b2[4]; } af;
#pragma unroll
      for (int jj = 0; jj < 4; ++jj) {
        float2 pr;
        pr.x = he_s * o[2 * jj];
        pr.y = he_s * o[2 * jj + 1];
        af.b2[jj] = __float22bfloat162_rn(pr);
      }
      acc = __builtin_amdgcn_mfma_f32_16x16x32_bf16(af.v, bfrag[s], acc, 0, 0, 0);
    }
    {  // bias step: A = o for k<16 (q=0,1 cover d=0..15), zero else
      union { short8 v; __hip_bfloat162 b2[4]; } af;
#pragma unroll
      for (int jj = 0; jj < 4; ++jj) {
        float2 pr;
        if (q < 2) { pr.x = o[2 * jj]; pr.y = o[2 * jj + 1]; }
        else { pr.x = 0.f; pr.y = 0.f; }
        af.b2[jj] = __float22bfloat162_rn(pr);
      }
      acc = __builtin_amdgcn_mfma_f32_16x16x32_bf16(af.v, bfrag[16], acc, 0, 0, 0);
    }

    int4 sl4 = *(const int4*)(slot + c * 16 + q * 4);
    m_buf[(size_t)sl4.x * 16 + n] = acc[0];
    m_buf[(size_t)sl4.y * 16 + n] = acc[1];
    m_buf[(size_t)sl4.z * 16 + n] = acc[2];
    m_buf[(size_t)sl4.w * 16 + n] = acc[3];
  }
}

// ---------------------------------------------------------------------------
// K3b: gather: agg[n,:] = sum over dst-sorted message range. 16 lanes/node.
// ---------------------------------------------------------------------------
__global__ __launch_bounds__(256) void gather_kernel(
    const int* __restrict__ row_off, const float* __restrict__ m_buf,
    float* __restrict__ agg) {
  int n = blockIdx.x * 16 + (threadIdx.x >> 4);
  int lane = threadIdx.x & 15;
  if (n >= N_NODES) return;
  int s = row_off[n], eend = row_off[n + 1];
  float sum = 0.f;
  for (int j = s; j < eend; ++j) sum += m_buf[(size_t)j * 16 + lane];
  agg[n * 16 + lane] = sum;
}

// ---------------------------------------------------------------------------
// K4: node update: m = relu(out@W_root + b_conv + agg/max(deg,1));
//     out = GRU(m, out)
// ---------------------------------------------------------------------------
__global__ __launch_bounds__(256) void gru_kernel(
    const float* __restrict__ Wroot, const float* __restrict__ bconv,
    const float* __restrict__ Wih, const float* __restrict__ bih,
    const float* __restrict__ Whh, const float* __restrict__ bhh,
    const float* __restrict__ agg, const int* __restrict__ degI,
    float* __restrict__ out) {
  int n = blockIdx.x * blockDim.x + threadIdx.x;
  if (n >= N_NODES) return;

  float hprev[16];
#pragma unroll
  for (int d = 0; d < 16; ++d) hprev[d] = out[n * 16 + d];
  float s = 1.0f / fmaxf((float)degI[n], 1.0f);

  float m[16];
#pragma unroll
  for (int k = 0; k < 16; ++k) {
    float a = bconv[k] + agg[n * 16 + k] * s;
#pragma unroll
    for (int d = 0; d < 16; ++d) a += hprev[d] * Wroot[d * 16 + k];
    m[k] = fmaxf(a, 0.f);
  }

  float hnew[16];
#pragma unroll
  for (int k = 0; k < 16; ++k) {
    float gir = bih[k], giz = bih[16 + k], gin = bih[32 + k];
    float ghr = bhh[k], ghz = bhh[16 + k], ghn = bhh[32 + k];
#pragma unroll
    for (int d = 0; d < 16; ++d) {
      gir += m[d] * Wih[k * 16 + d];
      giz += m[d] * Wih[(16 + k) * 16 + d];
      gin += m[d] * Wih[(32 + k) * 16 + d];
      ghr += hprev[d] * Whh[k * 16 + d];
      ghz += hprev[d] * Whh[(16 + k) * 16 + d];
      ghn += hprev[d] * Whh[(32 + k) * 16 + d];
    }
    float r = 1.f / (1.f + expf(-(gir + ghr)));
    float z = 1.f / (1.f + expf(-(giz + ghz)));
    float ng = tanhf(gin + r * ghn);
    hnew[k] = (1.f - z) * ng + z * hprev[k];
  }
#pragma unroll
  for (int k = 0; k < 16; ++k) out[n * 16 + k] = hnew[k];
}

// ---------------------------------------------------------------------------
// K5: post-GRU tail fused per node (only the out_edges branch is live).
// ---------------------------------------------------------------------------
__global__ __launch_bounds__(256) void final_kernel(
    const float* __restrict__ out, const int* __restrict__ node_type,
    const float* __restrict__ Wlin1, const float* __restrict__ blin1,
    const float* __restrict__ Wup, const float* __restrict__ bup,
    const float* __restrict__ Wdown, const float* __restrict__ bdown,
    const float* __restrict__ M_B, const float* __restrict__ M_A,
    const float* __restrict__ wedge, const float* __restrict__ Wline,
    const float* __restrict__ bline, float* __restrict__ res) {
  int n = blockIdx.x * blockDim.x + threadIdx.x;
  if (n >= N_NODES) return;

  float o[16];
#pragma unroll
  for (int d = 0; d < 16; ++d) o[d] = out[n * 16 + d];

  float oe[4];
#pragma unroll
  for (int b = 0; b < 4; ++b) {
    float a = blin1[b];
#pragma unroll
    for (int d = 0; d < 16; ++d) a += o[d] * Wlin1[d * 4 + b];
    oe[b] = fmaxf(a, 0.f);
  }

  bool ev = (node_type[n] == 2);
  float oc[16];
#pragma unroll
  for (int d = 0; d < 16; ++d) {
    float up = bup[d];
#pragma unroll
    for (int b = 0; b < 4; ++b) up += oe[b] * Wup[b * 16 + d];
    oc[d] = ev ? up : o[d];
  }

  float msgB[16];
#pragma unroll
  for (int k = 0; k < 16; ++k) {
    float a = 0.f;
#pragma unroll
    for (int d = 0; d < 16; ++d) a += oc[d] * M_B[d * 16 + k];
    msgB[k] = fmaxf(a, 0.f);
  }

  float oef[4];
#pragma unroll
  for (int b = 0; b < 4; ++b) {
    float mb = bdown[b];
#pragma unroll
    for (int k = 0; k < 16; ++k) mb += msgB[k] * Wdown[k * 4 + b];
    float ma = 0.f;
#pragma unroll
    for (int a = 0; a < 4; ++a) ma += oe[a] * M_A[a * 4 + b];
    ma = fmaxf(ma, 0.f);
    oef[b] = wedge[b] * (ma * mb);
  }

  float fin[4];
#pragma unroll
  for (int b = 0; b < 4; ++b) {
    float a = bline[b];
#pragma unroll
    for (int c = 0; c < 4; ++c) a += oef[c] * Wline[c * 4 + b];
    fin[b] = oe[b] + fmaxf(a, 0.f);
  }

  float mx = fmaxf(fmaxf(fin[0], fin[1]), fmaxf(fin[2], fin[3]));
  float se = expf(fin[0] - mx) + expf(fin[1] - mx) + expf(fin[2] - mx) +
             expf(fin[3] - mx);
  float lse = mx + logf(se);
#pragma unroll
  for (int b = 0; b < 4; ++b) res[n * 4 + b] = fin[b] - lse;
}

// ---------------------------------------------------------------------------
extern "C" void kernel_launch(void* const* d_in, const int* in_sizes, int n_in,
                              void* d_out, int out_size, void* d_ws,
                              size_t ws_size, hipStream_t stream) {
  const float* x       = (const float*)d_in[0];
  const int* node_type = (const int*)d_in[1];
  const int* ei        = (const int*)d_in[2];
  const float* ea      = (const float*)d_in[3];
  const float* W_lin0  = (const float*)d_in[4];
  const float* b_lin0  = (const float*)d_in[5];
  const float* W_root  = (const float*)d_in[6];
  const float* b_conv  = (const float*)d_in[7];
  const float* W_e1    = (const float*)d_in[8];
  const float* b_e1    = (const float*)d_in[9];
  const float* W_e2    = (const float*)d_in[10];
  const float* b_e2    = (const float*)d_in[11];
  const float* W_ih    = (const float*)d_in[12];
  const float* b_ih    = (const float*)d_in[13];
  const float* W_hh    = (const float*)d_in[14];
  const float* b_hh    = (const float*)d_in[15];
  const float* W_lin1  = (const float*)d_in[16];
  const float* b_lin1  = (const float*)d_in[17];
  const float* W_up    = (const float*)d_in[18];
  const float* b_up    = (const float*)d_in[19];
  const float* W_down  = (const float*)d_in[20];
  const float* b_down  = (const float*)d_in[21];
  const float* U_B     = (const float*)d_in[22];
  const float* V_B     = (const float*)d_in[23];
  // d_in[24..25] U_C,V_C and d_in[28..30] w_node,W_lin,b_lin : dead code
  const float* U_A     = (const float*)d_in[26];
  const float* V_A     = (const float*)d_in[27];
  const float* w_edge  = (const float*)d_in[31];
  const float* W_line  = (const float*)d_in[32];
  const float* b_line  = (const float*)d_in[33];

  float* ws    = (float*)d_ws;
  float* out   = ws;                              // N*16
  float* agg   = out + N_NODES * 16;              // N*16
  float* m_buf = agg + N_NODES * 16;              // E*16
  unsigned int* he_buf = (unsigned int*)(m_buf + (size_t)N_EDGES * 16);  // E*16 u32
  float* M_B   = (float*)(he_buf + (size_t)N_EDGES * 16);  // 256
  float* M_A   = M_B + 256;                       // 16
  int* degI    = (int*)(M_A + 16);                // N
  int* row_off = degI + N_NODES;                  // N+1
  int* blk_sum = row_off + N_NODES + 1;           // 256
  int* blk_off = blk_sum + 256;                   // 256
  int* cur     = blk_off + 256;                   // N
  int* slot    = cur + N_NODES;                   // E

  hipMemsetAsync(degI, 0, N_NODES * sizeof(int), stream);
  precompute_kernel<<<1, 256, 0, stream>>>(U_B, V_B, U_A, V_A, M_B, M_A);
  lin0_kernel<<<(N_NODES + 255) / 256, 256, 0, stream>>>(x, W_lin0, b_lin0, out);
  he_pre_kernel<<<(N_EDGES + 255) / 256, 256, 0, stream>>>(ea, W_e1, b_e1,
                                                           he_buf);

  // CSR build (once per launch; edge_index constant within a call)
  deg_count_kernel<<<(N_EDGES + 255) / 256, 256, 0, stream>>>(ei, degI);
  block_sum_kernel<<<NBLK, 256, 0, stream>>>(degI, blk_sum);
  block_scan_kernel<<<1, 256, 0, stream>>>(blk_sum, blk_off, row_off);
  node_scan_kernel<<<NBLK, 256, 0, stream>>>(degI, blk_off, row_off);
  hipMemcpyAsync(cur, row_off, N_NODES * sizeof(int),
                 hipMemcpyDeviceToDevice, stream);
  slot_kernel<<<(N_EDGES + 255) / 256, 256, 0, stream>>>(ei, cur, slot);

  for (int it = 0; it < 3; ++it) {
    edge_msg_mfma_kernel<<<EDGE_GRID, 256, 0, stream>>>(ei, he_buf, W_e2, b_e2,
                                                        out, slot, m_buf);
    gather_kernel<<<(N_NODES + 15) / 16, 256, 0, stream>>>(row_off, m_buf, agg);
    gru_kernel<<<(N_NODES + 255) / 256, 256, 0, stream>>>(
        W_root, b_conv, W_ih, b_ih, W_hh, b_hh, agg, degI, out);
  }

  final_kernel<<<(N_NODES + 255) / 256, 256, 0, stream>>>(
      out, node_type, W_lin1, b_lin1, W_up, b_up, W_down, b_down, M_B, M_A,
      w_edge, W_line, b_line, (float*)d_out);
}

// Round 4
// 372.611 us; speedup vs baseline: 3.9148x; 1.3319x over previous
//
#include <hip/hip_runtime.h>
#include <hip/hip_bf16.h>
#include <math.h>

#define N_NODES 50000
#define N_EDGES 400000
#define DIM 16
#define BOND 4
#define NBLK 196      // ceil(N_NODES/256)
#define NCHUNK 25000  // N_EDGES / 16
#define EDGE_GRID 784

typedef __attribute__((ext_vector_type(8))) short short8;
typedef __attribute__((ext_vector_type(4))) float f32x4;

// ---------------------------------------------------------------------------
// K0: M_B = U_B@V_B [16x16], M_A = U_A@V_A [4x4]. One wave per output
// element, 64-lane split over r + butterfly reduce. (msg_C / w_node / W_lin
// are dead code: only out_edges reaches the returned log_softmax.)
// ---------------------------------------------------------------------------
__global__ __launch_bounds__(256) void precompute_kernel(
    const float* __restrict__ U_B, const float* __restrict__ V_B,
    const float* __restrict__ U_A, const float* __restrict__ V_A,
    float* __restrict__ M_B, float* __restrict__ M_A) {
  int w = blockIdx.x * 4 + (threadIdx.x >> 6);
  int lane = threadIdx.x & 63;
  float partial = 0.f;
  if (w < 256) {
    int i = w >> 4, j = w & 15;
#pragma unroll
    for (int t = 0; t < 8; ++t) {
      int r = lane + 64 * t;
      partial += U_B[i * 512 + r] * V_B[r * 16 + j];
    }
  } else if (w < 272) {
    int a = (w - 256) >> 2, b = (w - 256) & 3;
#pragma unroll
    for (int t = 0; t < 8; ++t) {
      int r = lane + 64 * t;
      partial += U_A[a * 512 + r] * V_A[r * 4 + b];
    }
  }
#pragma unroll
  for (int off = 32; off > 0; off >>= 1) partial += __shfl_down(partial, off);
  if (lane == 0) {
    if (w < 256) M_B[w] = partial;
    else if (w < 272) M_A[w - 256] = partial;
  }
}

// ---------------------------------------------------------------------------
// K1: out = relu(x @ W_lin0 + b_lin0)   [N,16]
// ---------------------------------------------------------------------------
__global__ __launch_bounds__(256) void lin0_kernel(
    const float* __restrict__ x, const float* __restrict__ W,
    const float* __restrict__ b, float* __restrict__ out) {
  __shared__ float sW[256];
  __shared__ float sb[16];
  int t = threadIdx.x;
  sW[t] = W[t];
  if (t < 16) sb[t] = b[t];
  __syncthreads();
  int n = blockIdx.x * blockDim.x + t;
  if (n >= N_NODES) return;
  float xr[16];
#pragma unroll
  for (int d = 0; d < 16; ++d) xr[d] = x[n * 16 + d];
#pragma unroll
  for (int k = 0; k < 16; ++k) {
    float acc = sb[k];
#pragma unroll
    for (int d = 0; d < 16; ++d) acc += xr[d] * sW[d * 16 + k];
    out[n * 16 + k] = fmaxf(acc, 0.f);
  }
}

// ---------------------------------------------------------------------------
// CSR build (counting sort by dst). Int atomics only, once per launch.
// ---------------------------------------------------------------------------
__global__ __launch_bounds__(256) void deg_count_kernel(
    const int* __restrict__ ei, int* __restrict__ degI) {
  int e = blockIdx.x * 256 + threadIdx.x;
  if (e < N_EDGES) atomicAdd(&degI[ei[N_EDGES + e]], 1);
}

__global__ __launch_bounds__(256) void block_sum_kernel(
    const int* __restrict__ degI, int* __restrict__ blk) {
  __shared__ int s[256];
  int t = threadIdx.x;
  int n = blockIdx.x * 256 + t;
  s[t] = (n < N_NODES) ? degI[n] : 0;
  __syncthreads();
  for (int off = 128; off > 0; off >>= 1) {
    if (t < off) s[t] += s[t + off];
    __syncthreads();
  }
  if (t == 0) blk[blockIdx.x] = s[0];
}

__global__ __launch_bounds__(256) void block_scan_kernel(
    const int* __restrict__ blk, int* __restrict__ blk_off,
    int* __restrict__ row_off) {
  __shared__ int s[256];
  int t = threadIdx.x;
  int v = (t < NBLK) ? blk[t] : 0;
  s[t] = v;
  __syncthreads();
  for (int off = 1; off < 256; off <<= 1) {
    int x = (t >= off) ? s[t - off] : 0;
    __syncthreads();
    s[t] += x;
    __syncthreads();
  }
  if (t < NBLK) blk_off[t] = s[t] - v;  // exclusive
  if (t == 0) row_off[N_NODES] = N_EDGES;
}

// also seeds cur[] (slot cursor) to remove a separate d2d memcpy dispatch
__global__ __launch_bounds__(256) void node_scan_kernel(
    const int* __restrict__ degI, const int* __restrict__ blk_off,
    int* __restrict__ row_off, int* __restrict__ cur) {
  __shared__ int s[256];
  int t = threadIdx.x;
  int n = blockIdx.x * 256 + t;
  int d = (n < N_NODES) ? degI[n] : 0;
  s[t] = d;
  __syncthreads();
  for (int off = 1; off < 256; off <<= 1) {
    int x = (t >= off) ? s[t - off] : 0;
    __syncthreads();
    s[t] += x;
    __syncthreads();
  }
  if (n < N_NODES) {
    int v = blk_off[blockIdx.x] + s[t] - d;
    row_off[n] = v;
    cur[n] = v;
  }
}

__global__ __launch_bounds__(256) void slot_kernel(const int* __restrict__ ei,
                                                   int* __restrict__ cur,
                                                   int* __restrict__ slot) {
  int e = blockIdx.x * 256 + threadIdx.x;
  if (e < N_EDGES) slot[e] = atomicAdd(&cur[ei[N_EDGES + e]], 1);
}

// ---------------------------------------------------------------------------
// he precompute (iteration-invariant): he[e,h]=relu(b_e1[h]+ea[e,:]@W_e1[:,h])
// stored bf16, lane-fragment layout: he_buf[e*16 + p*8 + t] (uint32) packs
// (h = 4t+p) low half, (h = 4t+2+p) high half, p = parity in {0,1}.
// ---------------------------------------------------------------------------
__global__ __launch_bounds__(256) void he_pre_kernel(
    const float* __restrict__ ea, const float* __restrict__ We1,
    const float* __restrict__ be1, unsigned int* __restrict__ he_buf) {
  __shared__ float sW[128];
  __shared__ float sb[32];
  int t = threadIdx.x;
  if (t < 128) sW[t] = We1[t];
  if (t < 32) sb[t] = be1[t];
  __syncthreads();
  int e = blockIdx.x * 256 + t;
  if (e >= N_EDGES) return;
  float4 v = ((const float4*)ea)[e];
  float h[32];
#pragma unroll
  for (int k = 0; k < 32; ++k) {
    float a = sb[k] + v.x * sW[k] + v.y * sW[32 + k] + v.z * sW[64 + k] +
              v.w * sW[96 + k];
    h[k] = fmaxf(a, 0.f);
  }
  unsigned int u[16];
#pragma unroll
  for (int p = 0; p < 2; ++p)
#pragma unroll
    for (int tt = 0; tt < 8; ++tt) {
      float2 pr;
      pr.x = h[4 * tt + p];
      pr.y = h[4 * tt + 2 + p];
      __hip_bfloat162 b = __float22bfloat162_rn(pr);
      u[p * 8 + tt] = *(unsigned int*)&b;
    }
  uint4* dst = (uint4*)(he_buf + (size_t)e * 16);
#pragma unroll
  for (int qq = 0; qq < 4; ++qq)
    dst[qq] = make_uint4(u[4 * qq], u[4 * qq + 1], u[4 * qq + 2], u[4 * qq + 3]);
}

// ---------------------------------------------------------------------------
// K3 (MFMA): m[E,16] = Z[E,512] @ W2'[512,16],  Z[e, h*16+d] = he[e,h]*o[src,d]
// 16x16x32 bf16 MFMA, fp32 accumulate; B-fragments (all We2 + b_e2, bf16)
// preloaded in VGPRs once per wave; 16-edge chunks grid-strided.
// ---------------------------------------------------------------------------
__global__ __launch_bounds__(256) void edge_msg_mfma_kernel(
    const int* __restrict__ ei, const unsigned int* __restrict__ he_buf,
    const float* __restrict__ We2, const float* __restrict__ be2,
    const float* __restrict__ out, const int* __restrict__ slot,
    float* __restrict__ m_buf) {
  const int lane = threadIdx.x & 63;
  const int q = lane >> 4, n = lane & 15;
  const int p = q >> 1, dbase = (q & 1) * 8;

  short8 bfrag[17];
#pragma unroll
  for (int s = 0; s < 16; ++s) {
    int h = 2 * s + p;
    union { short8 v; __hip_bfloat162 b2[4]; } bf;
#pragma unroll
    for (int jj = 0; jj < 4; ++jj) {
      float2 w;
      w.x = We2[h * 256 + (dbase + 2 * jj) * 16 + n];
      w.y = We2[h * 256 + (dbase + 2 * jj + 1) * 16 + n];
      bf.b2[jj] = __float22bfloat162_rn(w);
    }
    bfrag[s] = bf.v;
  }
  {
    union { short8 v; __hip_bfloat162 b2[4]; } bf;
#pragma unroll
    for (int jj = 0; jj < 4; ++jj) {
      float2 w;
      if (q < 2) {
        w.x = be2[(dbase + 2 * jj) * 16 + n];
        w.y = be2[(dbase + 2 * jj + 1) * 16 + n];
      } else {
        w.x = 0.f; w.y = 0.f;
      }
      bf.b2[jj] = __float22bfloat162_rn(w);
    }
    bfrag[16] = bf.v;
  }

  int wave = blockIdx.x * 4 + (threadIdx.x >> 6);
  const int nw = EDGE_GRID * 4;
  for (int c = wave; c < NCHUNK; c += nw) {
    int e = c * 16 + n;
    int src = ei[e];
    const uint4* hp = (const uint4*)(he_buf + (size_t)e * 16 + p * 8);
    uint4 h0 = hp[0], h1 = hp[1];
    unsigned int heu[8] = {h0.x, h0.y, h0.z, h0.w, h1.x, h1.y, h1.z, h1.w};
    const float4* op = (const float4*)(out + src * 16 + dbase);
    float4 o0 = op[0], o1 = op[1];
    float o[8] = {o0.x, o0.y, o0.z, o0.w, o1.x, o1.y, o1.z, o1.w};

    f32x4 acc = {0.f, 0.f, 0.f, 0.f};
#pragma unroll
    for (int s = 0; s < 16; ++s) {
      unsigned int hw = heu[s >> 1];
      float he_s = __uint_as_float((s & 1) ? (hw & 0xffff0000u) : (hw << 16));
      union { short8 v; __hip_bfloat162 b2[4]; } af;
#pragma unroll
      for (int jj = 0; jj < 4; ++jj) {
        float2 pr;
        pr.x = he_s * o[2 * jj];
        pr.y = he_s * o[2 * jj + 1];
        af.b2[jj] = __float22bfloat162_rn(pr);
      }
      acc = __builtin_amdgcn_mfma_f32_16x16x32_bf16(af.v, bfrag[s], acc, 0, 0, 0);
    }
    {  // bias step
      union { short8 v; __hip_bfloat162 b2[4]; } af;
#pragma unroll
      for (int jj = 0; jj < 4; ++jj) {
        float2 pr;
        if (q < 2) { pr.x = o[2 * jj]; pr.y = o[2 * jj + 1]; }
        else { pr.x = 0.f; pr.y = 0.f; }
        af.b2[jj] = __float22bfloat162_rn(pr);
      }
      acc = __builtin_amdgcn_mfma_f32_16x16x32_bf16(af.v, bfrag[16], acc, 0, 0, 0);
    }

    int4 sl4 = *(const int4*)(slot + c * 16 + q * 4);
    m_buf[(size_t)sl4.x * 16 + n] = acc[0];
    m_buf[(size_t)sl4.y * 16 + n] = acc[1];
    m_buf[(size_t)sl4.z * 16 + n] = acc[2];
    m_buf[(size_t)sl4.w * 16 + n] = acc[3];
  }
}

// ---------------------------------------------------------------------------
// K4 (fused gather + GRU): 16 lanes per node. Lane k owns column k:
// gathers agg[k] over the node's dst-sorted m_buf range, then
// m = relu(out@W_root + b_conv + agg/deg) and the GRU via __shfl(.,d,16)
// broadcasts against LDS-staged weights (W_ih/W_hh transposed so lane-k
// reads are stride-1 -> conflict-free). Fast __expf sigmoid/tanh.
// ---------------------------------------------------------------------------
__global__ __launch_bounds__(256) void gather_gru_kernel(
    const int* __restrict__ row_off, const float* __restrict__ m_buf,
    const float* __restrict__ Wroot, const float* __restrict__ bconv,
    const float* __restrict__ Wih, const float* __restrict__ bih,
    const float* __restrict__ Whh, const float* __restrict__ bhh,
    float* __restrict__ out) {
  __shared__ float sWr[256];     // Wroot[d*16+k] (native layout)
  __shared__ float sWihT[768];   // [g*256 + d*16 + k] = Wih[(g*16+k)*16+d]
  __shared__ float sWhhT[768];
  __shared__ float sb[112];      // bconv[16] | bih[48] | bhh[48]
  int t = threadIdx.x;
  int kk = t >> 4, dd = t & 15;
  sWr[t] = Wroot[t];
#pragma unroll
  for (int g = 0; g < 3; ++g) {
    sWihT[g * 256 + dd * 16 + kk] = Wih[g * 256 + t];
    sWhhT[g * 256 + dd * 16 + kk] = Whh[g * 256 + t];
  }
  if (t < 16) sb[t] = bconv[t];
  else if (t < 64) sb[t] = bih[t - 16];
  else if (t < 112) sb[t] = bhh[t - 64];
  __syncthreads();

  int n = blockIdx.x * 16 + (t >> 4);
  int k = t & 15;
  int s0 = row_off[n], s1 = row_off[n + 1];

  float aggk = 0.f;
  for (int j = s0; j < s1; ++j) aggk += m_buf[(size_t)j * 16 + k];
  float sc = 1.f / fmaxf((float)(s1 - s0), 1.f);

  float hk = out[n * 16 + k];  // == out[blockIdx*256 + t], coalesced

  float mk = sb[k] + aggk * sc;
#pragma unroll
  for (int d = 0; d < 16; ++d) mk += __shfl(hk, d, 16) * sWr[d * 16 + k];
  mk = fmaxf(mk, 0.f);

  float gir = sb[16 + k], giz = sb[32 + k], gin = sb[48 + k];
  float ghr = sb[64 + k], ghz = sb[80 + k], ghn = sb[96 + k];
#pragma unroll
  for (int d = 0; d < 16; ++d) {
    float md = __shfl(mk, d, 16);
    float hd = __shfl(hk, d, 16);
    gir += md * sWihT[d * 16 + k];
    giz += md * sWihT[256 + d * 16 + k];
    gin += md * sWihT[512 + d * 16 + k];
    ghr += hd * sWhhT[d * 16 + k];
    ghz += hd * sWhhT[256 + d * 16 + k];
    ghn += hd * sWhhT[512 + d * 16 + k];
  }
  float r = 1.f / (1.f + __expf(-(gir + ghr)));
  float z = 1.f / (1.f + __expf(-(giz + ghz)));
  float xn = gin + r * ghn;
  float ng = 1.f - 2.f / (__expf(2.f * xn) + 1.f);  // tanh, saturates safely
  out[n * 16 + k] = (1.f - z) * ng + z * hk;
}

// ---------------------------------------------------------------------------
// K5: post-GRU tail fused per node (only the out_edges branch is live).
// ---------------------------------------------------------------------------
__global__ __launch_bounds__(256) void final_kernel(
    const float* __restrict__ out, const int* __restrict__ node_type,
    const float* __restrict__ Wlin1, const float* __restrict__ blin1,
    const float* __restrict__ Wup, const float* __restrict__ bup,
    const float* __restrict__ Wdown, const float* __restrict__ bdown,
    const float* __restrict__ M_B, const float* __restrict__ M_A,
    const float* __restrict__ wedge, const float* __restrict__ Wline,
    const float* __restrict__ bline, float* __restrict__ res) {
  int n = blockIdx.x * blockDim.x + threadIdx.x;
  if (n >= N_NODES) return;

  float o[16];
#pragma unroll
  for (int d = 0; d < 16; ++d) o[d] = out[n * 16 + d];

  float oe[4];
#pragma unroll
  for (int b = 0; b < 4; ++b) {
    float a = blin1[b];
#pragma unroll
    for (int d = 0; d < 16; ++d) a += o[d] * Wlin1[d * 4 + b];
    oe[b] = fmaxf(a, 0.f);
  }

  bool ev = (node_type[n] == 2);
  float oc[16];
#pragma unroll
  for (int d = 0; d < 16; ++d) {
    float up = bup[d];
#pragma unroll
    for (int b = 0; b < 4; ++b) up += oe[b] * Wup[b * 16 + d];
    oc[d] = ev ? up : o[d];
  }

  float msgB[16];
#pragma unroll
  for (int k = 0; k < 16; ++k) {
    float a = 0.f;
#pragma unroll
    for (int d = 0; d < 16; ++d) a += oc[d] * M_B[d * 16 + k];
    msgB[k] = fmaxf(a, 0.f);
  }

  float oef[4];
#pragma unroll
  for (int b = 0; b < 4; ++b) {
    float mb = bdown[b];
#pragma unroll
    for (int k = 0; k < 16; ++k) mb += msgB[k] * Wdown[k * 4 + b];
    float ma = 0.f;
#pragma unroll
    for (int a = 0; a < 4; ++a) ma += oe[a] * M_A[a * 4 + b];
    ma = fmaxf(ma, 0.f);
    oef[b] = wedge[b] * (ma * mb);
  }

  float fin[4];
#pragma unroll
  for (int b = 0; b < 4; ++b) {
    float a = bline[b];
#pragma unroll
    for (int c = 0; c < 4; ++c) a += oef[c] * Wline[c * 4 + b];
    fin[b] = oe[b] + fmaxf(a, 0.f);
  }

  float mx = fmaxf(fmaxf(fin[0], fin[1]), fmaxf(fin[2], fin[3]));
  float se = __expf(fin[0] - mx) + __expf(fin[1] - mx) + __expf(fin[2] - mx) +
             __expf(fin[3] - mx);
  float lse = mx + __logf(se);
#pragma unroll
  for (int b = 0; b < 4; ++b) res[n * 4 + b] = fin[b] - lse;
}

// ---------------------------------------------------------------------------
extern "C" void kernel_launch(void* const* d_in, const int* in_sizes, int n_in,
                              void* d_out, int out_size, void* d_ws,
                              size_t ws_size, hipStream_t stream) {
  const float* x       = (const float*)d_in[0];
  const int* node_type = (const int*)d_in[1];
  const int* ei        = (const int*)d_in[2];
  const float* ea      = (const float*)d_in[3];
  const float* W_lin0  = (const float*)d_in[4];
  const float* b_lin0  = (const float*)d_in[5];
  const float* W_root  = (const float*)d_in[6];
  const float* b_conv  = (const float*)d_in[7];
  const float* W_e1    = (const float*)d_in[8];
  const float* b_e1    = (const float*)d_in[9];
  const float* W_e2    = (const float*)d_in[10];
  const float* b_e2    = (const float*)d_in[11];
  const float* W_ih    = (const float*)d_in[12];
  const float* b_ih    = (const float*)d_in[13];
  const float* W_hh    = (const float*)d_in[14];
  const float* b_hh    = (const float*)d_in[15];
  const float* W_lin1  = (const float*)d_in[16];
  const float* b_lin1  = (const float*)d_in[17];
  const float* W_up    = (const float*)d_in[18];
  const float* b_up    = (const float*)d_in[19];
  const float* W_down  = (const float*)d_in[20];
  const float* b_down  = (const float*)d_in[21];
  const float* U_B     = (const float*)d_in[22];
  const float* V_B     = (const float*)d_in[23];
  // d_in[24..25] U_C,V_C and d_in[28..30] w_node,W_lin,b_lin : dead code
  const float* U_A     = (const float*)d_in[26];
  const float* V_A     = (const float*)d_in[27];
  const float* w_edge  = (const float*)d_in[31];
  const float* W_line  = (const float*)d_in[32];
  const float* b_line  = (const float*)d_in[33];

  float* ws    = (float*)d_ws;
  float* out   = ws;                              // N*16
  float* m_buf = out + N_NODES * 16;              // E*16
  unsigned int* he_buf = (unsigned int*)(m_buf + (size_t)N_EDGES * 16);  // E*16
  float* M_B   = (float*)(he_buf + (size_t)N_EDGES * 16);  // 256
  float* M_A   = M_B + 256;                       // 16
  int* degI    = (int*)(M_A + 16);                // N
  int* row_off = degI + N_NODES;                  // N+1
  int* blk_sum = row_off + N_NODES + 1;           // 256
  int* blk_off = blk_sum + 256;                   // 256
  int* cur     = blk_off + 256;                   // N
  int* slot    = cur + N_NODES;                   // E

  hipMemsetAsync(degI, 0, N_NODES * sizeof(int), stream);
  precompute_kernel<<<68, 256, 0, stream>>>(U_B, V_B, U_A, V_A, M_B, M_A);
  lin0_kernel<<<(N_NODES + 255) / 256, 256, 0, stream>>>(x, W_lin0, b_lin0, out);
  he_pre_kernel<<<(N_EDGES + 255) / 256, 256, 0, stream>>>(ea, W_e1, b_e1,
                                                           he_buf);

  // CSR build (once per launch; edge_index constant within a call)
  deg_count_kernel<<<(N_EDGES + 255) / 256, 256, 0, stream>>>(ei, degI);
  block_sum_kernel<<<NBLK, 256, 0, stream>>>(degI, blk_sum);
  block_scan_kernel<<<1, 256, 0, stream>>>(blk_sum, blk_off, row_off);
  node_scan_kernel<<<NBLK, 256, 0, stream>>>(degI, blk_off, row_off, cur);
  slot_kernel<<<(N_EDGES + 255) / 256, 256, 0, stream>>>(ei, cur, slot);

  for (int it = 0; it < 3; ++it) {
    edge_msg_mfma_kernel<<<EDGE_GRID, 256, 0, stream>>>(ei, he_buf, W_e2, b_e2,
                                                        out, slot, m_buf);
    gather_gru_kernel<<<N_NODES / 16, 256, 0, stream>>>(
        row_off, m_buf, W_root, b_conv, W_ih, b_ih, W_hh, b_hh, out);
  }

  final_kernel<<<(N_NODES + 255) / 256, 256, 0, stream>>>(
      out, node_type, W_lin1, b_lin1, W_up, b_up, W_down, b_down, M_B, M_A,
      w_edge, W_line, b_line, (float*)d_out);
}

// Round 5
// 344.791 us; speedup vs baseline: 4.2307x; 1.0807x over previous
//
#include <hip/hip_runtime.h>
#include <hip/hip_bf16.h>
#include <math.h>

#define N_NODES 50000
#define N_EDGES 400000
#define DIM 16
#define BOND 4
#define NCHUNK 25000  // N_EDGES / 16
#define EDGE_GRID 784
#define E_BLOCKS 1563          // ceil(N_EDGES/256)
#define PRE_BASE (E_BLOCKS - 68)
#define SCAN_TILE 1024
#define SCAN_BLOCKS 49         // ceil(N_NODES/1024)

typedef __attribute__((ext_vector_type(8))) short short8;
typedef __attribute__((ext_vector_type(4))) float f32x4;

__device__ __forceinline__ float bf16_to_f32(unsigned short v) {
  return __uint_as_float(((unsigned int)v) << 16);
}

// ---------------------------------------------------------------------------
// K0 (setup, fused): lin0 (ids < N), he_pre + deg_count (ids < E), and
// M_B = U_B@V_B / M_A = U_A@V_A on the last 68 blocks (272 waves, 64-lane
// r-split + butterfly). msg_C / w_node / W_lin are dead code (only out_edges
// reaches the returned log_softmax).
// he layout (bf16): he_buf[e*16 + p*8 + t] packs h=4t+p (lo) / h=4t+2+p (hi).
// ---------------------------------------------------------------------------
__global__ __launch_bounds__(256) void setup_kernel(
    const float* __restrict__ x, const float* __restrict__ W_lin0,
    const float* __restrict__ b_lin0, const float* __restrict__ ea,
    const float* __restrict__ We1, const float* __restrict__ be1,
    const int* __restrict__ ei, const float* __restrict__ U_B,
    const float* __restrict__ V_B, const float* __restrict__ U_A,
    const float* __restrict__ V_A, float* __restrict__ out,
    unsigned int* __restrict__ he_buf, int* __restrict__ degI,
    float* __restrict__ M_B, float* __restrict__ M_A) {
  __shared__ float sW0[256];
  __shared__ float sb0[16];
  __shared__ float sW1[128];
  __shared__ float sb1[32];
  int t = threadIdx.x;
  sW0[t] = W_lin0[t];
  if (t < 16) sb0[t] = b_lin0[t];
  if (t < 128) sW1[t] = We1[t];
  if (t < 32) sb1[t] = be1[t];
  __syncthreads();

  int gid = blockIdx.x * 256 + t;

  if (gid < N_NODES) {  // lin0
    float xr[16];
#pragma unroll
    for (int d = 0; d < 16; ++d) xr[d] = x[gid * 16 + d];
#pragma unroll
    for (int k = 0; k < 16; ++k) {
      float acc = sb0[k];
#pragma unroll
      for (int d = 0; d < 16; ++d) acc += xr[d] * sW0[d * 16 + k];
      out[gid * 16 + k] = fmaxf(acc, 0.f);
    }
  }

  if (gid < N_EDGES) {  // he_pre + deg_count
    float4 v = ((const float4*)ea)[gid];
    float h[32];
#pragma unroll
    for (int k = 0; k < 32; ++k) {
      float a = sb1[k] + v.x * sW1[k] + v.y * sW1[32 + k] + v.z * sW1[64 + k] +
                v.w * sW1[96 + k];
      h[k] = fmaxf(a, 0.f);
    }
    unsigned int u[16];
#pragma unroll
    for (int p = 0; p < 2; ++p)
#pragma unroll
      for (int tt = 0; tt < 8; ++tt) {
        float2 pr;
        pr.x = h[4 * tt + p];
        pr.y = h[4 * tt + 2 + p];
        __hip_bfloat162 b = __float22bfloat162_rn(pr);
        u[p * 8 + tt] = *(unsigned int*)&b;
      }
    uint4* dst = (uint4*)(he_buf + (size_t)gid * 16);
#pragma unroll
    for (int qq = 0; qq < 4; ++qq)
      dst[qq] =
          make_uint4(u[4 * qq], u[4 * qq + 1], u[4 * qq + 2], u[4 * qq + 3]);
    atomicAdd(&degI[ei[N_EDGES + gid]], 1);
  }

  if (blockIdx.x >= PRE_BASE) {  // M_B / M_A precompute
    int w = (blockIdx.x - PRE_BASE) * 4 + (t >> 6);
    int lane = t & 63;
    float partial = 0.f;
    if (w < 256) {
      int i = w >> 4, j = w & 15;
#pragma unroll
      for (int r8 = 0; r8 < 8; ++r8) {
        int r = lane + 64 * r8;
        partial += U_B[i * 512 + r] * V_B[r * 16 + j];
      }
    } else if (w < 272) {
      int a = (w - 256) >> 2, b = (w - 256) & 3;
#pragma unroll
      for (int r8 = 0; r8 < 8; ++r8) {
        int r = lane + 64 * r8;
        partial += U_A[a * 512 + r] * V_A[r * 4 + b];
      }
    }
#pragma unroll
    for (int off = 32; off > 0; off >>= 1)
      partial += __shfl_down(partial, off);
    if (lane == 0) {
      if (w < 256) M_B[w] = partial;
      else if (w < 272) M_A[w - 256] = partial;
    }
  }
}

// ---------------------------------------------------------------------------
// K1: single-dispatch exclusive scan of degI -> row_off (+cur), decoupled
// lookback. st[] packs (sum<<2)|state, state: 1=aggregate, 2=inclusive.
// 49 blocks, all co-resident (<=256 CUs) -> spin is safe.
// ---------------------------------------------------------------------------
__global__ __launch_bounds__(256) void scan_kernel(
    const int* __restrict__ degI, int* ticket, int* st,
    int* __restrict__ row_off, int* __restrict__ cur) {
  __shared__ int sdata[256];
  __shared__ int s_tile;
  __shared__ int s_base;
  int t = threadIdx.x;
  if (t == 0) s_tile = atomicAdd(ticket, 1);
  __syncthreads();
  int tile = s_tile;
  int n0 = tile * SCAN_TILE + t * 4;

  int d0 = (n0 + 0 < N_NODES) ? degI[n0 + 0] : 0;
  int d1 = (n0 + 1 < N_NODES) ? degI[n0 + 1] : 0;
  int d2 = (n0 + 2 < N_NODES) ? degI[n0 + 2] : 0;
  int d3 = (n0 + 3 < N_NODES) ? degI[n0 + 3] : 0;
  int tsum = d0 + d1 + d2 + d3;
  sdata[t] = tsum;
  __syncthreads();
  for (int off = 1; off < 256; off <<= 1) {
    int v = (t >= off) ? sdata[t - off] : 0;
    __syncthreads();
    sdata[t] += v;
    __syncthreads();
  }
  int excl = sdata[t] - tsum;
  int agg = sdata[255];

  if (t == 0) {
    if (tile == 0) {
      atomicExch(&st[0], (agg << 2) | 2);
      s_base = 0;
    } else {
      atomicExch(&st[tile], (agg << 2) | 1);
      int run = 0, idx = tile - 1;
      while (true) {
        int w = atomicAdd(&st[idx], 0);
        int stt = w & 3;
        if (stt == 2) { run += (w >> 2); break; }
        if (stt == 1) { run += (w >> 2); --idx; }
      }
      atomicExch(&st[tile], ((run + agg) << 2) | 2);
      s_base = run;
    }
  }
  __syncthreads();

  int pre = s_base + excl;
  if (n0 + 0 < N_NODES) { row_off[n0 + 0] = pre; cur[n0 + 0] = pre; }
  pre += d0;
  if (n0 + 1 < N_NODES) { row_off[n0 + 1] = pre; cur[n0 + 1] = pre; }
  pre += d1;
  if (n0 + 2 < N_NODES) { row_off[n0 + 2] = pre; cur[n0 + 2] = pre; }
  pre += d2;
  if (n0 + 3 < N_NODES) { row_off[n0 + 3] = pre; cur[n0 + 3] = pre; }
  if (tile == SCAN_BLOCKS - 1 && t == 0) row_off[N_NODES] = N_EDGES;
}

__global__ __launch_bounds__(256) void slot_kernel(const int* __restrict__ ei,
                                                   int* __restrict__ cur,
                                                   int* __restrict__ slot) {
  int e = blockIdx.x * 256 + threadIdx.x;
  if (e < N_EDGES) slot[e] = atomicAdd(&cur[ei[N_EDGES + e]], 1);
}

// ---------------------------------------------------------------------------
// K3 (MFMA): m[E,16] = Z[E,512] @ W2'[512,16],  Z[e, h*16+d] = he[e,h]*o[src,d]
// 16x16x32 bf16 MFMA, fp32 accumulate; B-fragments (all We2 + b_e2, bf16)
// preloaded in VGPRs once per wave; 16-edge chunks grid-strided; output
// written dst-sorted (slot) in bf16.
// ---------------------------------------------------------------------------
__global__ __launch_bounds__(256) void edge_msg_mfma_kernel(
    const int* __restrict__ ei, const unsigned int* __restrict__ he_buf,
    const float* __restrict__ We2, const float* __restrict__ be2,
    const float* __restrict__ out, const int* __restrict__ slot,
    unsigned short* __restrict__ m_bufh) {
  const int lane = threadIdx.x & 63;
  const int q = lane >> 4, n = lane & 15;
  const int p = q >> 1, dbase = (q & 1) * 8;

  short8 bfrag[17];
#pragma unroll
  for (int s = 0; s < 16; ++s) {
    int h = 2 * s + p;
    union { short8 v; __hip_bfloat162 b2[4]; } bf;
#pragma unroll
    for (int jj = 0; jj < 4; ++jj) {
      float2 w;
      w.x = We2[h * 256 + (dbase + 2 * jj) * 16 + n];
      w.y = We2[h * 256 + (dbase + 2 * jj + 1) * 16 + n];
      bf.b2[jj] = __float22bfloat162_rn(w);
    }
    bfrag[s] = bf.v;
  }
  {
    union { short8 v; __hip_bfloat162 b2[4]; } bf;
#pragma unroll
    for (int jj = 0; jj < 4; ++jj) {
      float2 w;
      if (q < 2) {
        w.x = be2[(dbase + 2 * jj) * 16 + n];
        w.y = be2[(dbase + 2 * jj + 1) * 16 + n];
      } else {
        w.x = 0.f; w.y = 0.f;
      }
      bf.b2[jj] = __float22bfloat162_rn(w);
    }
    bfrag[16] = bf.v;
  }

  int wave = blockIdx.x * 4 + (threadIdx.x >> 6);
  const int nw = EDGE_GRID * 4;
  for (int c = wave; c < NCHUNK; c += nw) {
    int e = c * 16 + n;
    int src = ei[e];
    const uint4* hp = (const uint4*)(he_buf + (size_t)e * 16 + p * 8);
    uint4 h0 = hp[0], h1 = hp[1];
    unsigned int heu[8] = {h0.x, h0.y, h0.z, h0.w, h1.x, h1.y, h1.z, h1.w};
    const float4* op = (const float4*)(out + src * 16 + dbase);
    float4 o0 = op[0], o1 = op[1];
    float o[8] = {o0.x, o0.y, o0.z, o0.w, o1.x, o1.y, o1.z, o1.w};

    f32x4 acc = {0.f, 0.f, 0.f, 0.f};
#pragma unroll
    for (int s = 0; s < 16; ++s) {
      unsigned int hw = heu[s >> 1];
      float he_s = __uint_as_float((s & 1) ? (hw & 0xffff0000u) : (hw << 16));
      union { short8 v; __hip_bfloat162 b2[4]; } af;
#pragma unroll
      for (int jj = 0; jj < 4; ++jj) {
        float2 pr;
        pr.x = he_s * o[2 * jj];
        pr.y = he_s * o[2 * jj + 1];
        af.b2[jj] = __float22bfloat162_rn(pr);
      }
      acc = __builtin_amdgcn_mfma_f32_16x16x32_bf16(af.v, bfrag[s], acc, 0, 0, 0);
    }
    {  // bias step
      union { short8 v; __hip_bfloat162 b2[4]; } af;
#pragma unroll
      for (int jj = 0; jj < 4; ++jj) {
        float2 pr;
        if (q < 2) { pr.x = o[2 * jj]; pr.y = o[2 * jj + 1]; }
        else { pr.x = 0.f; pr.y = 0.f; }
        af.b2[jj] = __float22bfloat162_rn(pr);
      }
      acc = __builtin_amdgcn_mfma_f32_16x16x32_bf16(af.v, bfrag[16], acc, 0, 0, 0);
    }

    int4 sl4 = *(const int4*)(slot + c * 16 + q * 4);
    __hip_bfloat16 b0 = __float2bfloat16(acc[0]);
    __hip_bfloat16 b1 = __float2bfloat16(acc[1]);
    __hip_bfloat16 b2 = __float2bfloat16(acc[2]);
    __hip_bfloat16 b3 = __float2bfloat16(acc[3]);
    m_bufh[(size_t)sl4.x * 16 + n] = *(unsigned short*)&b0;
    m_bufh[(size_t)sl4.y * 16 + n] = *(unsigned short*)&b1;
    m_bufh[(size_t)sl4.z * 16 + n] = *(unsigned short*)&b2;
    m_bufh[(size_t)sl4.w * 16 + n] = *(unsigned short*)&b3;
  }
}

// ---------------------------------------------------------------------------
// K4 (fused gather + GRU [+ final tail on last iter]): 16 lanes per node.
// Lane k owns column k. Weights LDS-staged (W_ih/W_hh transposed).
// do_final: compute the post-loop tail cooperatively (16-lane butterflies)
// and write log_softmax(out_edges) straight to res.
// ---------------------------------------------------------------------------
__global__ __launch_bounds__(256) void gather_gru_kernel(
    const int* __restrict__ row_off, const unsigned short* __restrict__ m_bufh,
    const float* __restrict__ Wroot, const float* __restrict__ bconv,
    const float* __restrict__ Wih, const float* __restrict__ bih,
    const float* __restrict__ Whh, const float* __restrict__ bhh,
    float* __restrict__ out, int do_final, const int* __restrict__ node_type,
    const float* __restrict__ Wlin1, const float* __restrict__ blin1,
    const float* __restrict__ Wup, const float* __restrict__ bup,
    const float* __restrict__ Wdown, const float* __restrict__ bdown,
    const float* __restrict__ M_B, const float* __restrict__ M_A,
    const float* __restrict__ wedge, const float* __restrict__ Wline,
    const float* __restrict__ bline, float* __restrict__ res) {
  __shared__ float sWr[256];
  __shared__ float sWihT[768];  // [g*256 + d*16 + k] = Wih[(g*16+k)*16+d]
  __shared__ float sWhhT[768];
  __shared__ float sb[112];     // bconv[16] | bih[48] | bhh[48]
  int t = threadIdx.x;
  int kk = t >> 4, dd = t & 15;
  sWr[t] = Wroot[t];
#pragma unroll
  for (int g = 0; g < 3; ++g) {
    sWihT[g * 256 + dd * 16 + kk] = Wih[g * 256 + t];
    sWhhT[g * 256 + dd * 16 + kk] = Whh[g * 256 + t];
  }
  if (t < 16) sb[t] = bconv[t];
  else if (t < 64) sb[t] = bih[t - 16];
  else if (t < 112) sb[t] = bhh[t - 64];
  __syncthreads();

  int n = blockIdx.x * 16 + (t >> 4);
  int k = t & 15;
  int s0 = row_off[n], s1 = row_off[n + 1];

  float aggk = 0.f;
  for (int j = s0; j < s1; ++j) aggk += bf16_to_f32(m_bufh[(size_t)j * 16 + k]);
  float sc = 1.f / fmaxf((float)(s1 - s0), 1.f);

  float hk = out[n * 16 + k];

  float mk = sb[k] + aggk * sc;
#pragma unroll
  for (int d = 0; d < 16; ++d) mk += __shfl(hk, d, 16) * sWr[d * 16 + k];
  mk = fmaxf(mk, 0.f);

  float gir = sb[16 + k], giz = sb[32 + k], gin = sb[48 + k];
  float ghr = sb[64 + k], ghz = sb[80 + k], ghn = sb[96 + k];
#pragma unroll
  for (int d = 0; d < 16; ++d) {
    float md = __shfl(mk, d, 16);
    float hd = __shfl(hk, d, 16);
    gir += md * sWihT[d * 16 + k];
    giz += md * sWihT[256 + d * 16 + k];
    gin += md * sWihT[512 + d * 16 + k];
    ghr += hd * sWhhT[d * 16 + k];
    ghz += hd * sWhhT[256 + d * 16 + k];
    ghn += hd * sWhhT[512 + d * 16 + k];
  }
  float r = 1.f / (1.f + __expf(-(gir + ghr)));
  float z = 1.f / (1.f + __expf(-(giz + ghz)));
  float xn = gin + r * ghn;
  float ng = 1.f - 2.f / (__expf(2.f * xn) + 1.f);  // tanh, saturates safely
  float hnew = (1.f - z) * ng + z * hk;

  if (!do_final) {
    out[n * 16 + k] = hnew;
    return;
  }

  // ---- fused tail (reference post-loop; only out_edges branch is live) ----
  // oe_b = relu(blin1_b + sum_k hnew_k * Wlin1[k*4+b])  via 16-lane butterfly
  float p0 = hnew * Wlin1[k * 4 + 0];
  float p1 = hnew * Wlin1[k * 4 + 1];
  float p2 = hnew * Wlin1[k * 4 + 2];
  float p3 = hnew * Wlin1[k * 4 + 3];
#pragma unroll
  for (int msk = 1; msk < 16; msk <<= 1) {
    p0 += __shfl_xor(p0, msk, 16);
    p1 += __shfl_xor(p1, msk, 16);
    p2 += __shfl_xor(p2, msk, 16);
    p3 += __shfl_xor(p3, msk, 16);
  }
  float oe0 = fmaxf(p0 + blin1[0], 0.f);
  float oe1 = fmaxf(p1 + blin1[1], 0.f);
  float oe2 = fmaxf(p2 + blin1[2], 0.f);
  float oe3 = fmaxf(p3 + blin1[3], 0.f);

  bool ev = (node_type[n] == 2);
  float ock = ev ? (bup[k] + oe0 * Wup[k] + oe1 * Wup[16 + k] +
                    oe2 * Wup[32 + k] + oe3 * Wup[48 + k])
                 : hnew;

  // msgB_k = relu(sum_d oc_d * M_B[d*16+k])
  float msgBk = 0.f;
#pragma unroll
  for (int d = 0; d < 16; ++d) msgBk += __shfl(ock, d, 16) * M_B[d * 16 + k];
  msgBk = fmaxf(msgBk, 0.f);

  // mtb_b = bdown_b + sum_k msgB_k * Wdown[k*4+b]  (no relu in reference)
  float q0 = msgBk * Wdown[k * 4 + 0];
  float q1 = msgBk * Wdown[k * 4 + 1];
  float q2 = msgBk * Wdown[k * 4 + 2];
  float q3 = msgBk * Wdown[k * 4 + 3];
#pragma unroll
  for (int msk = 1; msk < 16; msk <<= 1) {
    q0 += __shfl_xor(q0, msk, 16);
    q1 += __shfl_xor(q1, msk, 16);
    q2 += __shfl_xor(q2, msk, 16);
    q3 += __shfl_xor(q3, msk, 16);
  }
  float mtb0 = q0 + bdown[0], mtb1 = q1 + bdown[1];
  float mtb2 = q2 + bdown[2], mtb3 = q3 + bdown[3];

  // mta_b = relu(sum_a oe_a * M_A[a*4+b])  (redundant per lane, tiny)
  float mta0 = fmaxf(oe0 * M_A[0] + oe1 * M_A[4] + oe2 * M_A[8] + oe3 * M_A[12], 0.f);
  float mta1 = fmaxf(oe0 * M_A[1] + oe1 * M_A[5] + oe2 * M_A[9] + oe3 * M_A[13], 0.f);
  float mta2 = fmaxf(oe0 * M_A[2] + oe1 * M_A[6] + oe2 * M_A[10] + oe3 * M_A[14], 0.f);
  float mta3 = fmaxf(oe0 * M_A[3] + oe1 * M_A[7] + oe2 * M_A[11] + oe3 * M_A[15], 0.f);

  float c0 = wedge[0] * (mta0 * mtb0);
  float c1 = wedge[1] * (mta1 * mtb1);
  float c2 = wedge[2] * (mta2 * mtb2);
  float c3 = wedge[3] * (mta3 * mtb3);

  float f0 = oe0 + fmaxf(bline[0] + c0 * Wline[0] + c1 * Wline[4] +
                         c2 * Wline[8] + c3 * Wline[12], 0.f);
  float f1 = oe1 + fmaxf(bline[1] + c0 * Wline[1] + c1 * Wline[5] +
                         c2 * Wline[9] + c3 * Wline[13], 0.f);
  float f2 = oe2 + fmaxf(bline[2] + c0 * Wline[2] + c1 * Wline[6] +
                         c2 * Wline[10] + c3 * Wline[14], 0.f);
  float f3 = oe3 + fmaxf(bline[3] + c0 * Wline[3] + c1 * Wline[7] +
                         c2 * Wline[11] + c3 * Wline[15], 0.f);

  float mx = fmaxf(fmaxf(f0, f1), fmaxf(f2, f3));
  float se = __expf(f0 - mx) + __expf(f1 - mx) + __expf(f2 - mx) +
             __expf(f3 - mx);
  float lse = mx + __logf(se);
  if (k < 4) {
    float v = (k == 0) ? f0 : (k == 1) ? f1 : (k == 2) ? f2 : f3;
    res[n * 4 + k] = v - lse;
  }
}

// ---------------------------------------------------------------------------
extern "C" void kernel_launch(void* const* d_in, const int* in_sizes, int n_in,
                              void* d_out, int out_size, void* d_ws,
                              size_t ws_size, hipStream_t stream) {
  const float* x       = (const float*)d_in[0];
  const int* node_type = (const int*)d_in[1];
  const int* ei        = (const int*)d_in[2];
  const float* ea      = (const float*)d_in[3];
  const float* W_lin0  = (const float*)d_in[4];
  const float* b_lin0  = (const float*)d_in[5];
  const float* W_root  = (const float*)d_in[6];
  const float* b_conv  = (const float*)d_in[7];
  const float* W_e1    = (const float*)d_in[8];
  const float* b_e1    = (const float*)d_in[9];
  const float* W_e2    = (const float*)d_in[10];
  const float* b_e2    = (const float*)d_in[11];
  const float* W_ih    = (const float*)d_in[12];
  const float* b_ih    = (const float*)d_in[13];
  const float* W_hh    = (const float*)d_in[14];
  const float* b_hh    = (const float*)d_in[15];
  const float* W_lin1  = (const float*)d_in[16];
  const float* b_lin1  = (const float*)d_in[17];
  const float* W_up    = (const float*)d_in[18];
  const float* b_up    = (const float*)d_in[19];
  const float* W_down  = (const float*)d_in[20];
  const float* b_down  = (const float*)d_in[21];
  const float* U_B     = (const float*)d_in[22];
  const float* V_B     = (const float*)d_in[23];
  // d_in[24..25] U_C,V_C and d_in[28..30] w_node,W_lin,b_lin : dead code
  const float* U_A     = (const float*)d_in[26];
  const float* V_A     = (const float*)d_in[27];
  const float* w_edge  = (const float*)d_in[31];
  const float* W_line  = (const float*)d_in[32];
  const float* b_line  = (const float*)d_in[33];

  float* ws    = (float*)d_ws;
  float* out   = ws;                                        // N*16 f32
  unsigned int* he_buf = (unsigned int*)(out + N_NODES * 16);  // E*16 u32
  unsigned short* m_bufh =
      (unsigned short*)(he_buf + (size_t)N_EDGES * 16);     // E*16 u16
  float* M_B   = (float*)(m_bufh + (size_t)N_EDGES * 16);   // 256
  float* M_A   = M_B + 256;                                 // 16
  int* degI    = (int*)(M_A + 16);                          // N
  int* ticket  = degI + N_NODES;                            // 1
  int* st      = ticket + 1;                                // 63 (pad)
  int* row_off = st + 63;                                   // N+1
  int* cur     = row_off + N_NODES + 1;                     // N
  int* slot    = cur + N_NODES;                             // E

  // zero degI + ticket + st in one memset
  hipMemsetAsync(degI, 0, (N_NODES + 64) * sizeof(int), stream);

  setup_kernel<<<E_BLOCKS, 256, 0, stream>>>(
      x, W_lin0, b_lin0, ea, W_e1, b_e1, ei, U_B, V_B, U_A, V_A, out, he_buf,
      degI, M_B, M_A);
  scan_kernel<<<SCAN_BLOCKS, 256, 0, stream>>>(degI, ticket, st, row_off, cur);
  slot_kernel<<<E_BLOCKS, 256, 0, stream>>>(ei, cur, slot);

  for (int it = 0; it < 3; ++it) {
    edge_msg_mfma_kernel<<<EDGE_GRID, 256, 0, stream>>>(ei, he_buf, W_e2, b_e2,
                                                        out, slot, m_bufh);
    gather_gru_kernel<<<N_NODES / 16, 256, 0, stream>>>(
        row_off, m_bufh, W_root, b_conv, W_ih, b_ih, W_hh, b_hh, out,
        (it == 2) ? 1 : 0, node_type, W_lin1, b_lin1, W_up, b_up, W_down,
        b_down, M_B, M_A, w_edge, W_line, b_line, (float*)d_out);
  }
}